// Round 11
// baseline (381.745 us; speedup 1.0000x reference)
//
#include <hip/hip_runtime.h>
#include <hip/hip_bf16.h>

#define DIV_UP(a,b) (((a)+(b)-1)/(b))

#define CH   9216    // edges per partition block
#define CAP  7424    // max edges per 256-node bucket in sortfill (mean 4096)

typedef unsigned short ushort_t;
typedef unsigned int   uint_t;

__device__ __forceinline__ ushort_t f2bf(float f) {
    __hip_bfloat16 h = __float2bfloat16(f);   // RNE
    ushort_t u;
    __builtin_memcpy(&u, &h, 2);
    return u;
}
__device__ __forceinline__ float bfl(uint_t u) { return __uint_as_float(u << 16); }
__device__ __forceinline__ float bfh(uint_t u) { return __uint_as_float(u & 0xffff0000u); }

// ---------------- CSR build: bucketed counting sort ----------------
// bucket = dst >> 8 (256 nodes per bucket)

__global__ __launch_bounds__(256) void k_hist1(const int* __restrict__ dst, int E,
                                               int NBK, int NB1,
                                               int* __restrict__ blk_hist) {
    __shared__ int hist[512];
    for (int i = threadIdx.x; i < NBK; i += 256) hist[i] = 0;
    __syncthreads();
    int base = blockIdx.x * CH;
    int lim = E - base; if (lim > CH) lim = CH;
    for (int i = threadIdx.x; i < lim; i += 256)
        atomicAdd(&hist[dst[base + i] >> 8], 1);
    __syncthreads();
    for (int b = threadIdx.x; b < NBK; b += 256)
        blk_hist[b * NB1 + blockIdx.x] = hist[b];   // bucket-major
}

// ---- parallel scan, level 1: per-bucket row scan (bucket-local) + totals ----
__global__ __launch_bounds__(256) void k_rowscan(const int* __restrict__ blk_hist,
                                                 int* __restrict__ blk_off,
                                                 int* __restrict__ T,
                                                 int NB1) {
    __shared__ int s[256];
    int b = blockIdx.x;
    const int* row = blk_hist + (size_t)b * NB1;
    int* orow = blk_off + (size_t)b * NB1;
    int t = threadIdx.x;
    int K = DIV_UP(NB1, 256);
    int lo = t * K;
    int hi = lo + K; if (hi > NB1) hi = NB1;
    int sum = 0;
    for (int i = lo; i < hi; i++) sum += row[i];
    s[t] = sum;
    __syncthreads();
    for (int o = 1; o < 256; o <<= 1) {
        int v = (t >= o) ? s[t - o] : 0;
        __syncthreads();
        s[t] += v;
        __syncthreads();
    }
    int run = s[t] - sum;   // exclusive prefix of this thread's chunk
    for (int i = lo; i < hi; i++) { orow[i] = run; run += row[i]; }
    if (t == 255) T[b] = s[255];
}

// ---- parallel scan, level 2: scan of bucket totals (tiny) ----
__global__ __launch_bounds__(1024) void k_bktscan(const int* __restrict__ T,
                                                  int* __restrict__ bkt_base,
                                                  int NBK, int E) {
    __shared__ int s[1024];
    int t = threadIdx.x;
    int K = DIV_UP(NBK, 1024);
    int lo = t * K;
    int hi = lo + K; if (hi > NBK) hi = NBK;
    int sum = 0;
    for (int i = lo; i < hi; i++) sum += T[i];
    s[t] = sum;
    __syncthreads();
    for (int o = 1; o < 1024; o <<= 1) {
        int v = (t >= o) ? s[t - o] : 0;
        __syncthreads();
        s[t] += v;
        __syncthreads();
    }
    int run = s[t] - sum;
    for (int i = lo; i < hi; i++) { bkt_base[i] = run; run += T[i]; }
    if (t == 0) bkt_base[NBK] = E;
}

// ---- scatter: group edges by bucket in LDS, copy out coalesced ----
// (bkt_base added here; no separate addbase pass)

__global__ __launch_bounds__(256) void k_scatter1(const int* __restrict__ src,
                                                  const int* __restrict__ dst, int E,
                                                  int NBK, int NB1,
                                                  const int* __restrict__ blk_off,
                                                  const int* __restrict__ bkt_base,
                                                  unsigned int* __restrict__ part_arr) {
    __shared__ unsigned int   stage[CH];
    __shared__ unsigned short bko[CH];
    __shared__ int hist[512];
    __shared__ int cur[512];
    __shared__ int off[512];

    int t = threadIdx.x;
    hist[t] = 0; hist[t + 256] = 0;
    __syncthreads();

    int base = blockIdx.x * CH;
    int lim = E - base; if (lim > CH) lim = CH;

    for (int i = t; i < lim; i += 256)
        atomicAdd(&hist[dst[base + i] >> 8], 1);
    __syncthreads();

    int c0 = hist[t], c1 = hist[t + 256];
    for (int o = 1; o < 512; o <<= 1) {
        int v0 = (t >= o) ? hist[t - o] : 0;
        int v1 = hist[t + 256 - o];
        __syncthreads();
        hist[t] += v0;
        hist[t + 256] += v1;
        __syncthreads();
    }
    int e0 = hist[t] - c0;          // exclusive
    int e1 = hist[t + 256] - c1;
    cur[t] = e0; cur[t + 256] = e1;
    if (t < NBK)       off[t]       = blk_off[t * NB1 + blockIdx.x] + bkt_base[t] - e0;
    if (t + 256 < NBK) off[t + 256] = blk_off[(t + 256) * NB1 + blockIdx.x] + bkt_base[t + 256] - e1;
    __syncthreads();

    for (int i = t; i < lim; i += 256) {
        int d = dst[base + i];
        int sv = src[base + i];
        int b = d >> 8;
        int slot = atomicAdd(&cur[b], 1);
        stage[slot] = ((unsigned int)sv << 8) | (unsigned int)(d & 255);
        bko[slot] = (unsigned short)b;
    }
    __syncthreads();

    for (int i = t; i < lim; i += 256) {
        int b = bko[i];
        part_arr[off[b] + i] = stage[i];
    }
}

__global__ __launch_bounds__(256) void k_sortfill(const unsigned int* __restrict__ part_arr,
                                                  const int* __restrict__ bkt_base,
                                                  int N, int E,
                                                  int* __restrict__ col,
                                                  int* __restrict__ rowptr,
                                                  float* __restrict__ inv_sqrt) {
    __shared__ unsigned int in_[CAP];
    __shared__ int outS[CAP];
    __shared__ int hist[256];
    __shared__ int scn[256];
    __shared__ int cur[256];

    int b = blockIdx.x;
    int base = bkt_base[b];
    int nb   = bkt_base[b + 1] - base;
    int t = threadIdx.x;

    hist[t] = 0;
    __syncthreads();

    for (int i = t; i < nb; i += 256) {
        unsigned int pk = part_arr[base + i];
        in_[i] = pk;
        atomicAdd(&hist[pk & 255u], 1);
    }
    __syncthreads();

    int cnt = hist[t];
    for (int o = 1; o < 256; o <<= 1) {
        int v = (t >= o) ? hist[t - o] : 0;
        __syncthreads();
        hist[t] += v;
        __syncthreads();
    }
    int excl = hist[t] - cnt;
    scn[t] = excl;
    cur[t] = 0;
    __syncthreads();

    for (int i = t; i < nb; i += 256) {
        unsigned int pk = in_[i];
        int d = (int)(pk & 255u);
        int r = atomicAdd(&cur[d], 1);
        outS[scn[d] + r] = (int)(pk >> 8);
    }
    __syncthreads();

    for (int i = t; i < nb; i += 256) col[base + i] = outS[i];

    int node = b * 256 + t;
    if (node < N) {
        rowptr[node] = base + excl;
        inv_sqrt[node] = rsqrtf((float)(cnt + 1));   // +1: self-loop
    }
    if (b == 0 && t == 0) rowptr[N] = E;
}

// ---------------- Register-tiled GEMM, f32 or bf16 input, bf16 output ----------------
// outg[n][c] = bf16( inv_sqrt[n] * sum_k in[n][k]*W[k][c] )

template <bool BF16IN>
__global__ __launch_bounds__(256, 3) void k_gemm_rt(const void* __restrict__ inp,
                          const float* __restrict__ W,
                          const float* __restrict__ inv_sqrt,
                          ushort_t* __restrict__ outg, int N) {
    __shared__ float xsT[32][132];
    __shared__ float ws[32][132];

    const int t = threadIdx.x;
    const int row0 = blockIdx.x * 128;
    const int lane = t & 63;
    const int wave = t >> 6;
    const int rg = ((wave >> 1) << 3) + (lane >> 3);  // 0..15 row group
    const int cg = ((wave & 1) << 3) + (lane & 7);    // 0..15 col group

    const float4* W4 = (const float4*)W;

    float4 acc[8][2];
    #pragma unroll
    for (int i = 0; i < 8; i++) {
        acc[i][0] = make_float4(0.f, 0.f, 0.f, 0.f);
        acc[i][1] = make_float4(0.f, 0.f, 0.f, 0.f);
    }

    const bool full = (row0 + 128 <= N);

    for (int kt = 0; kt < 4; kt++) {
        if (BF16IN) {
            const uint4* in16 = (const uint4*)inp;   // row = 16 uint4 (128 bf16)
            #pragma unroll
            for (int i = 0; i < 2; i++) {
                int idx = t + i * 256;      // 0..511
                int r  = idx >> 2;          // 0..127
                int c8 = idx & 3;           // uint4 within kt slice (8 bf16)
                int row = row0 + r;
                uint4 v = make_uint4(0u, 0u, 0u, 0u);
                if (full || row < N) v = in16[(size_t)row * 16 + kt * 4 + c8];
                int kb = c8 * 8;
                xsT[kb + 0][r] = bfl(v.x); xsT[kb + 1][r] = bfh(v.x);
                xsT[kb + 2][r] = bfl(v.y); xsT[kb + 3][r] = bfh(v.y);
                xsT[kb + 4][r] = bfl(v.z); xsT[kb + 5][r] = bfh(v.z);
                xsT[kb + 6][r] = bfl(v.w); xsT[kb + 7][r] = bfh(v.w);
            }
        } else {
            const float4* in4 = (const float4*)inp;
            #pragma unroll
            for (int i = 0; i < 4; i++) {
                int idx = t + i * 256;
                int r  = idx >> 3;
                int c4 = idx & 7;
                int row = row0 + r;
                float4 v = make_float4(0.f, 0.f, 0.f, 0.f);
                if (full || row < N) v = in4[(size_t)row * 32 + kt * 8 + c4];
                xsT[c4 * 4 + 0][r] = v.x;
                xsT[c4 * 4 + 1][r] = v.y;
                xsT[c4 * 4 + 2][r] = v.z;
                xsT[c4 * 4 + 3][r] = v.w;
            }
        }
        #pragma unroll
        for (int i = 0; i < 4; i++) {
            int idx = t + i * 256;
            int kk = idx >> 5;
            int c4 = idx & 31;
            *(float4*)&ws[kk][c4 * 4] = W4[(size_t)(kt * 32 + kk) * 32 + c4];
        }
        __syncthreads();

        #pragma unroll 8
        for (int k = 0; k < 32; k++) {
            float4 a0 = *(const float4*)&xsT[k][rg * 8];
            float4 a1 = *(const float4*)&xsT[k][rg * 8 + 4];
            float4 b0 = *(const float4*)&ws[k][cg * 8];
            float4 b1 = *(const float4*)&ws[k][cg * 8 + 4];
            float av[8] = {a0.x, a0.y, a0.z, a0.w, a1.x, a1.y, a1.z, a1.w};
            #pragma unroll
            for (int i = 0; i < 8; i++) {
                acc[i][0].x += av[i] * b0.x;
                acc[i][0].y += av[i] * b0.y;
                acc[i][0].z += av[i] * b0.z;
                acc[i][0].w += av[i] * b0.w;
                acc[i][1].x += av[i] * b1.x;
                acc[i][1].y += av[i] * b1.y;
                acc[i][1].z += av[i] * b1.z;
                acc[i][1].w += av[i] * b1.w;
            }
        }
        __syncthreads();
    }

    #pragma unroll
    for (int i = 0; i < 8; i++) {
        int row = row0 + rg * 8 + i;
        if (full || row < N) {
            float s = inv_sqrt[row];
            float4 o0 = acc[i][0], o1 = acc[i][1];
            uint4 pk;
            pk.x = (uint_t)f2bf(s * o0.x) | ((uint_t)f2bf(s * o0.y) << 16);
            pk.y = (uint_t)f2bf(s * o0.z) | ((uint_t)f2bf(s * o0.w) << 16);
            pk.z = (uint_t)f2bf(s * o1.x) | ((uint_t)f2bf(s * o1.y) << 16);
            pk.w = (uint_t)f2bf(s * o1.z) | ((uint_t)f2bf(s * o1.w) << 16);
            ((uint4*)(outg + (size_t)row * 128))[cg] = pk;
        }
    }
}

// ---------------- Aggregate (bf16 gather -> bf16 out) ----------------
// h[n] = relu(inv_sqrt[n]*(sum g[col] + g[n]) + b), stored packed bf16.
// One wave per node (4 waves/block, no barrier), 8 gathers in flight,
// predicated dummy loads hit the self row (cache-hot).

__global__ __launch_bounds__(256) void k_agg(const ushort_t* __restrict__ g,
                            const int* __restrict__ rowptr,
                            const int* __restrict__ col, const float* __restrict__ inv_sqrt,
                            const float* __restrict__ bias, ushort_t* __restrict__ outh, int N) {
    int wid  = (blockIdx.x * blockDim.x + threadIdx.x) >> 6;   // node
    int lane = threadIdx.x & 63;
    if (wid >= N) return;

    int start = rowptr[wid];
    int end   = rowptr[wid + 1];

    const uint_t* g1 = (const uint_t*)g;    // row = 64 uints (128 bf16)
    float accx = 0.f, accy = 0.f;

    for (int tt = start; tt < end; tt += 8) {
        int idx[8];
        #pragma unroll
        for (int i = 0; i < 8; i++)
            idx[i] = (tt + i < end) ? col[tt + i] : wid;
        uint_t v[8];
        #pragma unroll
        for (int i = 0; i < 8; i++)
            v[i] = g1[(size_t)((unsigned)idx[i] * 64u + (unsigned)lane)];
        #pragma unroll
        for (int i = 0; i < 8; i++) {
            if (tt + i < end) {
                accx += bfl(v[i]);
                accy += bfh(v[i]);
            }
        }
    }

    uint_t sv = g1[(unsigned)wid * 64u + (unsigned)lane];
    accx += bfl(sv);
    accy += bfh(sv);

    float is = inv_sqrt[wid];
    float2 b = ((const float2*)bias)[lane];
    float ox = fmaxf(fmaf(is, accx, b.x), 0.f);
    float oy = fmaxf(fmaf(is, accy, b.y), 0.f);
    uint_t pk = (uint_t)f2bf(ox) | ((uint_t)f2bf(oy) << 16);
    ((uint_t*)outh)[(size_t)wid * 64 + lane] = pk;
}

// ---------------- Pool (bf16 h input) ----------------

__global__ void k_pool(const ushort_t* __restrict__ h, const int* __restrict__ batch,
                       float* __restrict__ pooled, int* __restrict__ counts, int N) {
    int f = threadIdx.x;            // 0..127
    int start = blockIdx.x * 256;
    int end = start + 256; if (end > N) end = N;
    if (start >= N) return;

    int cur = batch[start];
    float acc = 0.f;
    int cnt = 0;
    for (int r = start; r < end; r++) {
        int gi = batch[r];
        if (gi != cur) {
            atomicAdd(&pooled[(size_t)cur * 128 + f], acc);
            if (f == 0) atomicAdd(&counts[cur], cnt);
            acc = 0.f; cnt = 0; cur = gi;
        }
        acc += __uint_as_float((uint_t)h[(size_t)r * 128 + f] << 16);
        cnt++;
    }
    atomicAdd(&pooled[(size_t)cur * 128 + f], acc);
    if (f == 0) atomicAdd(&counts[cur], cnt);
}

// ---------------- MLP head ----------------

__global__ void k_mlp(const float* __restrict__ pooled, const int* __restrict__ counts,
                      const float* __restrict__ Wc1, const float* __restrict__ bc1,
                      const float* __restrict__ Wc2, const float* __restrict__ bc2,
                      float* __restrict__ out, int G) {
    int g = blockIdx.x;
    int j = threadIdx.x;    // 0..63
    __shared__ float pm[128];
    __shared__ float z[64];

    float invc = 1.0f / fmaxf((float)counts[g], 1.0f);
    pm[j]      = pooled[(size_t)g * 128 + j] * invc;
    pm[j + 64] = pooled[(size_t)g * 128 + 64 + j] * invc;
    __syncthreads();

    float a = bc1[j];
    #pragma unroll 8
    for (int k = 0; k < 128; k++) a += pm[k] * Wc1[k * 64 + j];
    z[j] = fmaxf(a, 0.f);
    __syncthreads();

    if (j < 8) {
        float o = bc2[j];
        #pragma unroll 8
        for (int k = 0; k < 64; k++) o += z[k] * Wc2[k * 8 + j];
        out[(size_t)g * 8 + j] = o;
    }
}

// ---------------- launch ----------------

extern "C" void kernel_launch(void* const* d_in, const int* in_sizes, int n_in,
                              void* d_out, int out_size, void* d_ws, size_t ws_size,
                              hipStream_t stream) {
    const float* x    = (const float*)d_in[0];
    const int*   ei   = (const int*)d_in[1];
    const int*   batch= (const int*)d_in[2];
    const float* W1   = (const float*)d_in[4];
    const float* b1   = (const float*)d_in[5];
    const float* W2   = (const float*)d_in[6];
    const float* b2   = (const float*)d_in[7];
    const float* Wc1  = (const float*)d_in[8];
    const float* bc1  = (const float*)d_in[9];
    const float* Wc2  = (const float*)d_in[10];
    const float* bc2  = (const float*)d_in[11];
    float* out = (float*)d_out;

    const int N = in_sizes[0] / 128;
    const int E = in_sizes[1] / 2;
    const int G = out_size / 8;

    const int* src = ei;
    const int* dst = ei + E;

    const int NBK = DIV_UP(N, 256);     // buckets of 256 nodes
    const int NB1 = DIV_UP(E, CH);      // partition blocks

    char* p = (char*)d_ws;
    auto alloc = [&](size_t bytes) {
        char* q = p;
        p += (bytes + 255) & ~(size_t)255;
        return q;
    };
    ushort_t* bufG1    = (ushort_t*)alloc((size_t)N * 128 * 2);  // g1 / h2 (bf16)
    ushort_t* bufG2    = (ushort_t*)alloc((size_t)N * 128 * 2);  // g2 (bf16)
    ushort_t* bufH     = (ushort_t*)alloc((size_t)N * 128 * 2);  // h1 (bf16)
    int*      rowptr   = (int*)     alloc(((size_t)N + 1) * 4);
    int*      colA     = (int*)     alloc((size_t)E * 4);
    float*    inv_sqrt = (float*)   alloc((size_t)N * 4);
    int*      blk_hist = (int*)     alloc((size_t)NBK * NB1 * 4);
    int*      blk_off  = (int*)     alloc((size_t)NBK * NB1 * 4);
    int*      bkt_base = (int*)     alloc(((size_t)NBK + 1) * 4);
    int*      bktT     = (int*)     alloc((size_t)NBK * 4);
    float*    pooled   = (float*)   alloc((size_t)G * 128 * 4);
    int*      counts   = (int*)     alloc((size_t)G * 4);

    // part_arr aliases bufG1: consumed by k_sortfill before GEMM1 writes bufG1
    unsigned int* part_arr = (unsigned int*)bufG1;

    hipMemsetAsync(pooled, 0, (size_t)G * 128 * 4, stream);
    hipMemsetAsync(counts, 0, (size_t)G * 4, stream);

    // CSR build (bucketed counting sort, parallel scan, addbase folded into scatter)
    k_hist1<<<NB1, 256, 0, stream>>>(dst, E, NBK, NB1, blk_hist);
    k_rowscan<<<NBK, 256, 0, stream>>>(blk_hist, blk_off, bktT, NB1);
    k_bktscan<<<1, 1024, 0, stream>>>(bktT, bkt_base, NBK, E);
    k_scatter1<<<NB1, 256, 0, stream>>>(src, dst, E, NBK, NB1, blk_off, bkt_base, part_arr);
    k_sortfill<<<NBK, 256, 0, stream>>>(part_arr, bkt_base, N, E, colA, rowptr, inv_sqrt);

    // layer 1: GEMM (f32 in) -> g1 bf16 ; aggregate -> h1 bf16
    k_gemm_rt<false><<<DIV_UP(N, 128), 256, 0, stream>>>(x, W1, inv_sqrt, bufG1, N);
    k_agg<<<DIV_UP(N, 4), 256, 0, stream>>>(bufG1, rowptr, colA, inv_sqrt, b1, bufH, N);

    // layer 2: GEMM (bf16 in) -> g2 bf16 ; aggregate -> h2 bf16 (reuse bufG1)
    k_gemm_rt<true><<<DIV_UP(N, 128), 256, 0, stream>>>(bufH, W2, inv_sqrt, bufG2, N);
    k_agg<<<DIV_UP(N, 4), 256, 0, stream>>>(bufG2, rowptr, colA, inv_sqrt, b2, bufG1, N);

    // pool + head
    k_pool<<<DIV_UP(N, 256), 128, 0, stream>>>(bufG1, batch, pooled, counts, N);
    k_mlp<<<G, 64, 0, stream>>>(pooled, counts, Wc1, bc1, Wc2, bc2, out, G);
}

// Round 12
// 353.607 us; speedup vs baseline: 1.0796x; 1.0796x over previous
//
#include <hip/hip_runtime.h>
#include <hip/hip_bf16.h>

#define DIV_UP(a,b) (((a)+(b)-1)/(b))

#define CH   9216    // edges per partition block
#define CAP  7424    // max edges per 256-node bucket in sortfill (mean 4096)

typedef unsigned short ushort_t;
typedef unsigned int   uint_t;

__device__ __forceinline__ ushort_t f2bf(float f) {
    __hip_bfloat16 h = __float2bfloat16(f);   // RNE
    ushort_t u;
    __builtin_memcpy(&u, &h, 2);
    return u;
}
__device__ __forceinline__ float bfl(uint_t u) { return __uint_as_float(u << 16); }
__device__ __forceinline__ float bfh(uint_t u) { return __uint_as_float(u & 0xffff0000u); }

// ---------------- CSR build: bucketed counting sort ----------------
// bucket = dst >> 8 (256 nodes per bucket)

__global__ __launch_bounds__(256) void k_hist1(const int* __restrict__ dst, int E,
                                               int NBK, int NB1,
                                               int* __restrict__ blk_hist) {
    __shared__ int hist[512];
    for (int i = threadIdx.x; i < NBK; i += 256) hist[i] = 0;
    __syncthreads();
    int base = blockIdx.x * CH;
    int lim = E - base; if (lim > CH) lim = CH;
    for (int i = threadIdx.x; i < lim; i += 256)
        atomicAdd(&hist[dst[base + i] >> 8], 1);
    __syncthreads();
    for (int b = threadIdx.x; b < NBK; b += 256)
        blk_hist[b * NB1 + blockIdx.x] = hist[b];   // bucket-major
}

// ---- parallel scan, level 1: per-bucket row scan (bucket-local) + totals ----
__global__ __launch_bounds__(256) void k_rowscan(const int* __restrict__ blk_hist,
                                                 int* __restrict__ blk_off,
                                                 int* __restrict__ T,
                                                 int NB1) {
    __shared__ int s[256];
    int b = blockIdx.x;
    const int* row = blk_hist + (size_t)b * NB1;
    int* orow = blk_off + (size_t)b * NB1;
    int t = threadIdx.x;
    int K = DIV_UP(NB1, 256);
    int lo = t * K;
    int hi = lo + K; if (hi > NB1) hi = NB1;
    int sum = 0;
    for (int i = lo; i < hi; i++) sum += row[i];
    s[t] = sum;
    __syncthreads();
    for (int o = 1; o < 256; o <<= 1) {
        int v = (t >= o) ? s[t - o] : 0;
        __syncthreads();
        s[t] += v;
        __syncthreads();
    }
    int run = s[t] - sum;   // exclusive prefix of this thread's chunk
    for (int i = lo; i < hi; i++) { orow[i] = run; run += row[i]; }
    if (t == 255) T[b] = s[255];
}

// ---- parallel scan, level 2: scan of bucket totals (tiny) ----
__global__ __launch_bounds__(1024) void k_bktscan(const int* __restrict__ T,
                                                  int* __restrict__ bkt_base,
                                                  int NBK, int E) {
    __shared__ int s[1024];
    int t = threadIdx.x;
    int K = DIV_UP(NBK, 1024);
    int lo = t * K;
    int hi = lo + K; if (hi > NBK) hi = NBK;
    int sum = 0;
    for (int i = lo; i < hi; i++) sum += T[i];
    s[t] = sum;
    __syncthreads();
    for (int o = 1; o < 1024; o <<= 1) {
        int v = (t >= o) ? s[t - o] : 0;
        __syncthreads();
        s[t] += v;
        __syncthreads();
    }
    int run = s[t] - sum;
    for (int i = lo; i < hi; i++) { bkt_base[i] = run; run += T[i]; }
    if (t == 0) bkt_base[NBK] = E;
}

// ---- scatter: group edges by bucket in LDS, copy out coalesced ----
// (bkt_base added here; no separate addbase pass)

__global__ __launch_bounds__(256) void k_scatter1(const int* __restrict__ src,
                                                  const int* __restrict__ dst, int E,
                                                  int NBK, int NB1,
                                                  const int* __restrict__ blk_off,
                                                  const int* __restrict__ bkt_base,
                                                  unsigned int* __restrict__ part_arr) {
    __shared__ unsigned int   stage[CH];
    __shared__ unsigned short bko[CH];
    __shared__ int hist[512];
    __shared__ int cur[512];
    __shared__ int off[512];

    int t = threadIdx.x;
    hist[t] = 0; hist[t + 256] = 0;
    __syncthreads();

    int base = blockIdx.x * CH;
    int lim = E - base; if (lim > CH) lim = CH;

    for (int i = t; i < lim; i += 256)
        atomicAdd(&hist[dst[base + i] >> 8], 1);
    __syncthreads();

    int c0 = hist[t], c1 = hist[t + 256];
    for (int o = 1; o < 512; o <<= 1) {
        int v0 = (t >= o) ? hist[t - o] : 0;
        int v1 = hist[t + 256 - o];
        __syncthreads();
        hist[t] += v0;
        hist[t + 256] += v1;
        __syncthreads();
    }
    int e0 = hist[t] - c0;          // exclusive
    int e1 = hist[t + 256] - c1;
    cur[t] = e0; cur[t + 256] = e1;
    if (t < NBK)       off[t]       = blk_off[t * NB1 + blockIdx.x] + bkt_base[t] - e0;
    if (t + 256 < NBK) off[t + 256] = blk_off[(t + 256) * NB1 + blockIdx.x] + bkt_base[t + 256] - e1;
    __syncthreads();

    for (int i = t; i < lim; i += 256) {
        int d = dst[base + i];
        int sv = src[base + i];
        int b = d >> 8;
        int slot = atomicAdd(&cur[b], 1);
        stage[slot] = ((unsigned int)sv << 8) | (unsigned int)(d & 255);
        bko[slot] = (unsigned short)b;
    }
    __syncthreads();

    for (int i = t; i < lim; i += 256) {
        int b = bko[i];
        part_arr[off[b] + i] = stage[i];
    }
}

__global__ __launch_bounds__(256) void k_sortfill(const unsigned int* __restrict__ part_arr,
                                                  const int* __restrict__ bkt_base,
                                                  int N, int E,
                                                  int* __restrict__ col,
                                                  int* __restrict__ rowptr,
                                                  float* __restrict__ inv_sqrt) {
    __shared__ unsigned int in_[CAP];
    __shared__ int outS[CAP];
    __shared__ int hist[256];
    __shared__ int scn[256];
    __shared__ int cur[256];

    int b = blockIdx.x;
    int base = bkt_base[b];
    int nb   = bkt_base[b + 1] - base;
    int t = threadIdx.x;

    hist[t] = 0;
    __syncthreads();

    for (int i = t; i < nb; i += 256) {
        unsigned int pk = part_arr[base + i];
        in_[i] = pk;
        atomicAdd(&hist[pk & 255u], 1);
    }
    __syncthreads();

    int cnt = hist[t];
    for (int o = 1; o < 256; o <<= 1) {
        int v = (t >= o) ? hist[t - o] : 0;
        __syncthreads();
        hist[t] += v;
        __syncthreads();
    }
    int excl = hist[t] - cnt;
    scn[t] = excl;
    cur[t] = 0;
    __syncthreads();

    for (int i = t; i < nb; i += 256) {
        unsigned int pk = in_[i];
        int d = (int)(pk & 255u);
        int r = atomicAdd(&cur[d], 1);
        outS[scn[d] + r] = (int)(pk >> 8);
    }
    __syncthreads();

    for (int i = t; i < nb; i += 256) col[base + i] = outS[i];

    int node = b * 256 + t;
    if (node < N) {
        rowptr[node] = base + excl;
        inv_sqrt[node] = rsqrtf((float)(cnt + 1));   // +1: self-loop
    }
    if (b == 0 && t == 0) rowptr[N] = E;
}

// ---------------- Register-tiled GEMM, f32 or bf16 input, bf16 output ----------------
// outg[n][c] = bf16( inv_sqrt[n] * sum_k in[n][k]*W[k][c] )

template <bool BF16IN>
__global__ __launch_bounds__(256, 3) void k_gemm_rt(const void* __restrict__ inp,
                          const float* __restrict__ W,
                          const float* __restrict__ inv_sqrt,
                          ushort_t* __restrict__ outg, int N) {
    __shared__ float xsT[32][132];
    __shared__ float ws[32][132];

    const int t = threadIdx.x;
    const int row0 = blockIdx.x * 128;
    const int lane = t & 63;
    const int wave = t >> 6;
    const int rg = ((wave >> 1) << 3) + (lane >> 3);  // 0..15 row group
    const int cg = ((wave & 1) << 3) + (lane & 7);    // 0..15 col group

    const float4* W4 = (const float4*)W;

    float4 acc[8][2];
    #pragma unroll
    for (int i = 0; i < 8; i++) {
        acc[i][0] = make_float4(0.f, 0.f, 0.f, 0.f);
        acc[i][1] = make_float4(0.f, 0.f, 0.f, 0.f);
    }

    const bool full = (row0 + 128 <= N);

    for (int kt = 0; kt < 4; kt++) {
        if (BF16IN) {
            const uint4* in16 = (const uint4*)inp;   // row = 16 uint4 (128 bf16)
            #pragma unroll
            for (int i = 0; i < 2; i++) {
                int idx = t + i * 256;      // 0..511
                int r  = idx >> 2;          // 0..127
                int c8 = idx & 3;           // uint4 within kt slice (8 bf16)
                int row = row0 + r;
                uint4 v = make_uint4(0u, 0u, 0u, 0u);
                if (full || row < N) v = in16[(size_t)row * 16 + kt * 4 + c8];
                int kb = c8 * 8;
                xsT[kb + 0][r] = bfl(v.x); xsT[kb + 1][r] = bfh(v.x);
                xsT[kb + 2][r] = bfl(v.y); xsT[kb + 3][r] = bfh(v.y);
                xsT[kb + 4][r] = bfl(v.z); xsT[kb + 5][r] = bfh(v.z);
                xsT[kb + 6][r] = bfl(v.w); xsT[kb + 7][r] = bfh(v.w);
            }
        } else {
            const float4* in4 = (const float4*)inp;
            #pragma unroll
            for (int i = 0; i < 4; i++) {
                int idx = t + i * 256;
                int r  = idx >> 3;
                int c4 = idx & 7;
                int row = row0 + r;
                float4 v = make_float4(0.f, 0.f, 0.f, 0.f);
                if (full || row < N) v = in4[(size_t)row * 32 + kt * 8 + c4];
                xsT[c4 * 4 + 0][r] = v.x;
                xsT[c4 * 4 + 1][r] = v.y;
                xsT[c4 * 4 + 2][r] = v.z;
                xsT[c4 * 4 + 3][r] = v.w;
            }
        }
        #pragma unroll
        for (int i = 0; i < 4; i++) {
            int idx = t + i * 256;
            int kk = idx >> 5;
            int c4 = idx & 31;
            *(float4*)&ws[kk][c4 * 4] = W4[(size_t)(kt * 32 + kk) * 32 + c4];
        }
        __syncthreads();

        #pragma unroll 8
        for (int k = 0; k < 32; k++) {
            float4 a0 = *(const float4*)&xsT[k][rg * 8];
            float4 a1 = *(const float4*)&xsT[k][rg * 8 + 4];
            float4 b0 = *(const float4*)&ws[k][cg * 8];
            float4 b1 = *(const float4*)&ws[k][cg * 8 + 4];
            float av[8] = {a0.x, a0.y, a0.z, a0.w, a1.x, a1.y, a1.z, a1.w};
            #pragma unroll
            for (int i = 0; i < 8; i++) {
                acc[i][0].x += av[i] * b0.x;
                acc[i][0].y += av[i] * b0.y;
                acc[i][0].z += av[i] * b0.z;
                acc[i][0].w += av[i] * b0.w;
                acc[i][1].x += av[i] * b1.x;
                acc[i][1].y += av[i] * b1.y;
                acc[i][1].z += av[i] * b1.z;
                acc[i][1].w += av[i] * b1.w;
            }
        }
        __syncthreads();
    }

    #pragma unroll
    for (int i = 0; i < 8; i++) {
        int row = row0 + rg * 8 + i;
        if (full || row < N) {
            float s = inv_sqrt[row];
            float4 o0 = acc[i][0], o1 = acc[i][1];
            uint4 pk;
            pk.x = (uint_t)f2bf(s * o0.x) | ((uint_t)f2bf(s * o0.y) << 16);
            pk.y = (uint_t)f2bf(s * o0.z) | ((uint_t)f2bf(s * o0.w) << 16);
            pk.z = (uint_t)f2bf(s * o1.x) | ((uint_t)f2bf(s * o1.y) << 16);
            pk.w = (uint_t)f2bf(s * o1.z) | ((uint_t)f2bf(s * o1.w) << 16);
            ((uint4*)(outg + (size_t)row * 128))[cg] = pk;
        }
    }
}

// ---------------- Aggregate (bf16 gather -> bf16 out) ----------------
// h[n] = relu(inv_sqrt[n]*(sum g[col] + g[n]) + b), stored packed bf16.
// One wave per node (4 waves/block, no barrier), 8 gathers in flight,
// predicated dummy loads hit the self row (cache-hot).

__global__ __launch_bounds__(256) void k_agg(const ushort_t* __restrict__ g,
                            const int* __restrict__ rowptr,
                            const int* __restrict__ col, const float* __restrict__ inv_sqrt,
                            const float* __restrict__ bias, ushort_t* __restrict__ outh, int N) {
    int wid  = (blockIdx.x * blockDim.x + threadIdx.x) >> 6;   // node
    int lane = threadIdx.x & 63;
    if (wid >= N) return;

    int start = rowptr[wid];
    int end   = rowptr[wid + 1];

    const uint_t* g1 = (const uint_t*)g;    // row = 64 uints (128 bf16)
    float accx = 0.f, accy = 0.f;

    for (int tt = start; tt < end; tt += 8) {
        int idx[8];
        #pragma unroll
        for (int i = 0; i < 8; i++)
            idx[i] = (tt + i < end) ? col[tt + i] : wid;
        uint_t v[8];
        #pragma unroll
        for (int i = 0; i < 8; i++)
            v[i] = g1[(size_t)((unsigned)idx[i] * 64u + (unsigned)lane)];
        #pragma unroll
        for (int i = 0; i < 8; i++) {
            if (tt + i < end) {
                accx += bfl(v[i]);
                accy += bfh(v[i]);
            }
        }
    }

    uint_t sv = g1[(unsigned)wid * 64u + (unsigned)lane];
    accx += bfl(sv);
    accy += bfh(sv);

    float is = inv_sqrt[wid];
    float2 b = ((const float2*)bias)[lane];
    float ox = fmaxf(fmaf(is, accx, b.x), 0.f);
    float oy = fmaxf(fmaf(is, accy, b.y), 0.f);
    uint_t pk = (uint_t)f2bf(ox) | ((uint_t)f2bf(oy) << 16);
    ((uint_t*)outh)[(size_t)wid * 64 + lane] = pk;
}

// ---------------- Pool v2: parallel, wave = 16 rows, lane = feature pair ----------------
// Phase 1: issue all 16 row loads + batch loads (in flight together).
// Phase 2: register-serial run detection over sorted batch, one atomicAdd
// pair per (run, lane). ~200K atomics total, negligible contention.

__global__ __launch_bounds__(256) void k_pool(const ushort_t* __restrict__ h,
                       const int* __restrict__ batch,
                       float* __restrict__ pooled, int* __restrict__ counts, int N) {
    int w    = threadIdx.x >> 6;          // wave 0..3
    int lane = threadIdx.x & 63;
    int row0 = blockIdx.x * 64 + w * 16;
    if (row0 >= N) return;
    int nr = N - row0; if (nr > 16) nr = 16;

    const uint_t* h1 = (const uint_t*)h;

    uint_t v[16];
    int    bb[16];
    #pragma unroll
    for (int i = 0; i < 16; i++) {
        int r = (i < nr) ? row0 + i : row0;
        v[i]  = h1[(size_t)r * 64 + lane];
        bb[i] = batch[r];
    }

    float ax = 0.f, ay = 0.f;
    int cnt = 0;
    int cur = bb[0];
    #pragma unroll
    for (int i = 0; i < 16; i++) {
        if (i < nr) {
            if (bb[i] != cur) {
                atomicAdd(&pooled[(size_t)cur * 128 + lane * 2],     ax);
                atomicAdd(&pooled[(size_t)cur * 128 + lane * 2 + 1], ay);
                if (lane == 0) atomicAdd(&counts[cur], cnt);
                ax = 0.f; ay = 0.f; cnt = 0; cur = bb[i];
            }
            ax += bfl(v[i]);
            ay += bfh(v[i]);
            cnt++;
        }
    }
    atomicAdd(&pooled[(size_t)cur * 128 + lane * 2],     ax);
    atomicAdd(&pooled[(size_t)cur * 128 + lane * 2 + 1], ay);
    if (lane == 0) atomicAdd(&counts[cur], cnt);
}

// ---------------- MLP head ----------------

__global__ void k_mlp(const float* __restrict__ pooled, const int* __restrict__ counts,
                      const float* __restrict__ Wc1, const float* __restrict__ bc1,
                      const float* __restrict__ Wc2, const float* __restrict__ bc2,
                      float* __restrict__ out, int G) {
    int g = blockIdx.x;
    int j = threadIdx.x;    // 0..63
    __shared__ float pm[128];
    __shared__ float z[64];

    float invc = 1.0f / fmaxf((float)counts[g], 1.0f);
    pm[j]      = pooled[(size_t)g * 128 + j] * invc;
    pm[j + 64] = pooled[(size_t)g * 128 + 64 + j] * invc;
    __syncthreads();

    float a = bc1[j];
    #pragma unroll 8
    for (int k = 0; k < 128; k++) a += pm[k] * Wc1[k * 64 + j];
    z[j] = fmaxf(a, 0.f);
    __syncthreads();

    if (j < 8) {
        float o = bc2[j];
        #pragma unroll 8
        for (int k = 0; k < 64; k++) o += z[k] * Wc2[k * 8 + j];
        out[(size_t)g * 8 + j] = o;
    }
}

// ---------------- launch ----------------

extern "C" void kernel_launch(void* const* d_in, const int* in_sizes, int n_in,
                              void* d_out, int out_size, void* d_ws, size_t ws_size,
                              hipStream_t stream) {
    const float* x    = (const float*)d_in[0];
    const int*   ei   = (const int*)d_in[1];
    const int*   batch= (const int*)d_in[2];
    const float* W1   = (const float*)d_in[4];
    const float* b1   = (const float*)d_in[5];
    const float* W2   = (const float*)d_in[6];
    const float* b2   = (const float*)d_in[7];
    const float* Wc1  = (const float*)d_in[8];
    const float* bc1  = (const float*)d_in[9];
    const float* Wc2  = (const float*)d_in[10];
    const float* bc2  = (const float*)d_in[11];
    float* out = (float*)d_out;

    const int N = in_sizes[0] / 128;
    const int E = in_sizes[1] / 2;
    const int G = out_size / 8;

    const int* src = ei;
    const int* dst = ei + E;

    const int NBK = DIV_UP(N, 256);     // buckets of 256 nodes
    const int NB1 = DIV_UP(E, CH);      // partition blocks

    char* p = (char*)d_ws;
    auto alloc = [&](size_t bytes) {
        char* q = p;
        p += (bytes + 255) & ~(size_t)255;
        return q;
    };
    ushort_t* bufG1    = (ushort_t*)alloc((size_t)N * 128 * 2);  // g1 / h2 (bf16)
    ushort_t* bufG2    = (ushort_t*)alloc((size_t)N * 128 * 2);  // g2 (bf16)
    ushort_t* bufH     = (ushort_t*)alloc((size_t)N * 128 * 2);  // h1 (bf16)
    int*      rowptr   = (int*)     alloc(((size_t)N + 1) * 4);
    int*      colA     = (int*)     alloc((size_t)E * 4);
    float*    inv_sqrt = (float*)   alloc((size_t)N * 4);
    int*      blk_hist = (int*)     alloc((size_t)NBK * NB1 * 4);
    int*      blk_off  = (int*)     alloc((size_t)NBK * NB1 * 4);
    int*      bkt_base = (int*)     alloc(((size_t)NBK + 1) * 4);
    int*      bktT     = (int*)     alloc((size_t)NBK * 4);
    float*    pooled   = (float*)   alloc((size_t)G * 128 * 4);
    int*      counts   = (int*)     alloc((size_t)G * 4);

    // part_arr aliases bufG1: consumed by k_sortfill before GEMM1 writes bufG1
    unsigned int* part_arr = (unsigned int*)bufG1;

    hipMemsetAsync(pooled, 0, (size_t)G * 128 * 4, stream);
    hipMemsetAsync(counts, 0, (size_t)G * 4, stream);

    // CSR build (bucketed counting sort, parallel scan, addbase folded into scatter)
    k_hist1<<<NB1, 256, 0, stream>>>(dst, E, NBK, NB1, blk_hist);
    k_rowscan<<<NBK, 256, 0, stream>>>(blk_hist, blk_off, bktT, NB1);
    k_bktscan<<<1, 1024, 0, stream>>>(bktT, bkt_base, NBK, E);
    k_scatter1<<<NB1, 256, 0, stream>>>(src, dst, E, NBK, NB1, blk_off, bkt_base, part_arr);
    k_sortfill<<<NBK, 256, 0, stream>>>(part_arr, bkt_base, N, E, colA, rowptr, inv_sqrt);

    // layer 1: GEMM (f32 in) -> g1 bf16 ; aggregate -> h1 bf16
    k_gemm_rt<false><<<DIV_UP(N, 128), 256, 0, stream>>>(x, W1, inv_sqrt, bufG1, N);
    k_agg<<<DIV_UP(N, 4), 256, 0, stream>>>(bufG1, rowptr, colA, inv_sqrt, b1, bufH, N);

    // layer 2: GEMM (bf16 in) -> g2 bf16 ; aggregate -> h2 bf16 (reuse bufG1)
    k_gemm_rt<true><<<DIV_UP(N, 128), 256, 0, stream>>>(bufH, W2, inv_sqrt, bufG2, N);
    k_agg<<<DIV_UP(N, 4), 256, 0, stream>>>(bufG2, rowptr, colA, inv_sqrt, b2, bufG1, N);

    // pool + head
    k_pool<<<DIV_UP(N, 64), 256, 0, stream>>>(bufG1, batch, pooled, counts, N);
    k_mlp<<<G, 64, 0, stream>>>(pooled, counts, Wc1, bc1, Wc2, bc2, out, G);
}

// Round 13
// 296.634 us; speedup vs baseline: 1.2869x; 1.1921x over previous
//
#include <hip/hip_runtime.h>
#include <hip/hip_bf16.h>

#define DIV_UP(a,b) (((a)+(b)-1)/(b))

#define CH   9216    // edges per partition block
#define CAP  7424    // max edges per 256-node bucket in sortfill (mean 4096)

typedef unsigned short ushort_t;
typedef unsigned int   uint_t;
typedef __attribute__((ext_vector_type(8))) short bf16x8;   // 8 bf16 = 4 VGPR
typedef __attribute__((ext_vector_type(4))) float f32x4;

__device__ __forceinline__ ushort_t f2bf(float f) {
    __hip_bfloat16 h = __float2bfloat16(f);   // RNE
    ushort_t u;
    __builtin_memcpy(&u, &h, 2);
    return u;
}
__device__ __forceinline__ float bfl(uint_t u) { return __uint_as_float(u << 16); }
__device__ __forceinline__ float bfh(uint_t u) { return __uint_as_float(u & 0xffff0000u); }

// ---------------- CSR build: bucketed counting sort ----------------
// bucket = dst >> 8 (256 nodes per bucket)

__global__ __launch_bounds__(256) void k_hist1(const int* __restrict__ dst, int E,
                                               int NBK, int NB1,
                                               int* __restrict__ blk_hist) {
    __shared__ int hist[512];
    for (int i = threadIdx.x; i < NBK; i += 256) hist[i] = 0;
    __syncthreads();
    int base = blockIdx.x * CH;
    int lim = E - base; if (lim > CH) lim = CH;
    for (int i = threadIdx.x; i < lim; i += 256)
        atomicAdd(&hist[dst[base + i] >> 8], 1);
    __syncthreads();
    for (int b = threadIdx.x; b < NBK; b += 256)
        blk_hist[b * NB1 + blockIdx.x] = hist[b];   // bucket-major
}

// ---- parallel scan, level 1: per-bucket row scan (bucket-local) + totals ----
__global__ __launch_bounds__(256) void k_rowscan(const int* __restrict__ blk_hist,
                                                 int* __restrict__ blk_off,
                                                 int* __restrict__ T,
                                                 int NB1) {
    __shared__ int s[256];
    int b = blockIdx.x;
    const int* row = blk_hist + (size_t)b * NB1;
    int* orow = blk_off + (size_t)b * NB1;
    int t = threadIdx.x;
    int K = DIV_UP(NB1, 256);
    int lo = t * K;
    int hi = lo + K; if (hi > NB1) hi = NB1;
    int sum = 0;
    for (int i = lo; i < hi; i++) sum += row[i];
    s[t] = sum;
    __syncthreads();
    for (int o = 1; o < 256; o <<= 1) {
        int v = (t >= o) ? s[t - o] : 0;
        __syncthreads();
        s[t] += v;
        __syncthreads();
    }
    int run = s[t] - sum;   // exclusive prefix of this thread's chunk
    for (int i = lo; i < hi; i++) { orow[i] = run; run += row[i]; }
    if (t == 255) T[b] = s[255];
}

// ---- parallel scan, level 2: scan of bucket totals (tiny) ----
__global__ __launch_bounds__(1024) void k_bktscan(const int* __restrict__ T,
                                                  int* __restrict__ bkt_base,
                                                  int NBK, int E) {
    __shared__ int s[1024];
    int t = threadIdx.x;
    int K = DIV_UP(NBK, 1024);
    int lo = t * K;
    int hi = lo + K; if (hi > NBK) hi = NBK;
    int sum = 0;
    for (int i = lo; i < hi; i++) sum += T[i];
    s[t] = sum;
    __syncthreads();
    for (int o = 1; o < 1024; o <<= 1) {
        int v = (t >= o) ? s[t - o] : 0;
        __syncthreads();
        s[t] += v;
        __syncthreads();
    }
    int run = s[t] - sum;
    for (int i = lo; i < hi; i++) { bkt_base[i] = run; run += T[i]; }
    if (t == 0) bkt_base[NBK] = E;
}

// ---- scatter: group edges by bucket in LDS, copy out coalesced ----

__global__ __launch_bounds__(256) void k_scatter1(const int* __restrict__ src,
                                                  const int* __restrict__ dst, int E,
                                                  int NBK, int NB1,
                                                  const int* __restrict__ blk_off,
                                                  const int* __restrict__ bkt_base,
                                                  unsigned int* __restrict__ part_arr) {
    __shared__ unsigned int   stage[CH];
    __shared__ unsigned short bko[CH];
    __shared__ int hist[512];
    __shared__ int cur[512];
    __shared__ int off[512];

    int t = threadIdx.x;
    hist[t] = 0; hist[t + 256] = 0;
    __syncthreads();

    int base = blockIdx.x * CH;
    int lim = E - base; if (lim > CH) lim = CH;

    for (int i = t; i < lim; i += 256)
        atomicAdd(&hist[dst[base + i] >> 8], 1);
    __syncthreads();

    int c0 = hist[t], c1 = hist[t + 256];
    for (int o = 1; o < 512; o <<= 1) {
        int v0 = (t >= o) ? hist[t - o] : 0;
        int v1 = hist[t + 256 - o];
        __syncthreads();
        hist[t] += v0;
        hist[t + 256] += v1;
        __syncthreads();
    }
    int e0 = hist[t] - c0;          // exclusive
    int e1 = hist[t + 256] - c1;
    cur[t] = e0; cur[t + 256] = e1;
    if (t < NBK)       off[t]       = blk_off[t * NB1 + blockIdx.x] + bkt_base[t] - e0;
    if (t + 256 < NBK) off[t + 256] = blk_off[(t + 256) * NB1 + blockIdx.x] + bkt_base[t + 256] - e1;
    __syncthreads();

    for (int i = t; i < lim; i += 256) {
        int d = dst[base + i];
        int sv = src[base + i];
        int b = d >> 8;
        int slot = atomicAdd(&cur[b], 1);
        stage[slot] = ((unsigned int)sv << 8) | (unsigned int)(d & 255);
        bko[slot] = (unsigned short)b;
    }
    __syncthreads();

    for (int i = t; i < lim; i += 256) {
        int b = bko[i];
        part_arr[off[b] + i] = stage[i];
    }
}

__global__ __launch_bounds__(256) void k_sortfill(const unsigned int* __restrict__ part_arr,
                                                  const int* __restrict__ bkt_base,
                                                  int N, int E,
                                                  int* __restrict__ col,
                                                  int* __restrict__ rowptr,
                                                  float* __restrict__ inv_sqrt) {
    __shared__ unsigned int in_[CAP];
    __shared__ int outS[CAP];
    __shared__ int hist[256];
    __shared__ int scn[256];
    __shared__ int cur[256];

    int b = blockIdx.x;
    int base = bkt_base[b];
    int nb   = bkt_base[b + 1] - base;
    int t = threadIdx.x;

    hist[t] = 0;
    __syncthreads();

    for (int i = t; i < nb; i += 256) {
        unsigned int pk = part_arr[base + i];
        in_[i] = pk;
        atomicAdd(&hist[pk & 255u], 1);
    }
    __syncthreads();

    int cnt = hist[t];
    for (int o = 1; o < 256; o <<= 1) {
        int v = (t >= o) ? hist[t - o] : 0;
        __syncthreads();
        hist[t] += v;
        __syncthreads();
    }
    int excl = hist[t] - cnt;
    scn[t] = excl;
    cur[t] = 0;
    __syncthreads();

    for (int i = t; i < nb; i += 256) {
        unsigned int pk = in_[i];
        int d = (int)(pk & 255u);
        int r = atomicAdd(&cur[d], 1);
        outS[scn[d] + r] = (int)(pk >> 8);
    }
    __syncthreads();

    for (int i = t; i < nb; i += 256) col[base + i] = outS[i];

    int node = b * 256 + t;
    if (node < N) {
        rowptr[node] = base + excl;
        inv_sqrt[node] = rsqrtf((float)(cnt + 1));   // +1: self-loop
    }
    if (b == 0 && t == 0) rowptr[N] = E;
}

// ---------------- W prep: wT[c][k] = bf16(W[k][c]) for both layers ----------------

__global__ __launch_bounds__(256) void k_prepW(const float* __restrict__ W1,
                                               const float* __restrict__ W2,
                                               ushort_t* __restrict__ wT1,
                                               ushort_t* __restrict__ wT2) {
    int idx = blockIdx.x * 256 + threadIdx.x;   // grid 128 blocks = 32768
    const float* W = (idx < 16384) ? W1 : W2;
    ushort_t*    O = (idx < 16384) ? wT1 : wT2;
    int j = idx & 16383;
    int k = j >> 7, c = j & 127;
    O[c * 128 + k] = f2bf(W[j]);
}

// ---------------- MFMA GEMM: outg[n][c] = bf16(inv_sqrt[n] * (X @ W)[n][c]) ----------------
// 128x128 tile, 4 waves, each wave = 64x64 quadrant of 4x4 16x16 fragments.
// Computes D^T = (W^T)(X^T) via operand swap: lane holds one node's 4
// consecutive output cols per acc reg -> single inv_sqrt + packed uint2 store.
// LDS row stride 56 bf16 (112 B): 16B-aligned b128 reads, 2-way banks (free).

template <bool BF16IN>
__global__ __launch_bounds__(256) void k_gemm_mfma(const void* __restrict__ inp,
                        const ushort_t* __restrict__ wT,   // [128 c][128 k] bf16
                        const float* __restrict__ inv_sqrt,
                        ushort_t* __restrict__ outg, int N) {
    __shared__ ushort_t xs[128][56];   // [node][k]
    __shared__ ushort_t ws[128][56];   // [col][k]
    __shared__ float ivs[128];

    const int t = threadIdx.x;
    const int row0 = blockIdx.x * 128;
    const int lane = t & 63;
    const int wv = t >> 6;
    const int wrN = wv >> 1;        // node quadrant *64
    const int wcC = wv & 1;         // col quadrant *64
    const int lh = lane >> 4;       // 0..3
    const int ll = lane & 15;

    const bool full = (row0 + 128 <= N);

    if (t < 128) {
        int r = row0 + t;
        ivs[t] = inv_sqrt[(full || r < N) ? r : 0];
    }

    f32x4 acc[4][4];   // [cb][nb]
    #pragma unroll
    for (int a = 0; a < 4; a++)
        #pragma unroll
        for (int b = 0; b < 4; b++)
            acc[a][b] = (f32x4){0.f, 0.f, 0.f, 0.f};

    const uint4* wT16 = (const uint4*)wT;   // row = 16 uint4

    for (int kt = 0; kt < 4; kt++) {
        if (BF16IN) {
            const uint4* in16 = (const uint4*)inp;
            #pragma unroll
            for (int i = 0; i < 2; i++) {
                int fq = t + i * 256;       // 0..511
                int r = fq >> 2, q = fq & 3;
                int row = row0 + r;
                uint4 v = make_uint4(0u, 0u, 0u, 0u);
                if (full || row < N) v = in16[(size_t)row * 16 + kt * 4 + q];
                *(uint4*)&xs[r][q * 8] = v;
            }
        } else {
            const float4* in4 = (const float4*)inp;
            #pragma unroll
            for (int i = 0; i < 4; i++) {
                int fq = t + i * 256;       // 0..1023
                int r = fq >> 3, q = fq & 7;
                int row = row0 + r;
                float4 v = make_float4(0.f, 0.f, 0.f, 0.f);
                if (full || row < N) v = in4[(size_t)row * 32 + kt * 8 + q];
                uint2 u;
                u.x = (uint_t)f2bf(v.x) | ((uint_t)f2bf(v.y) << 16);
                u.y = (uint_t)f2bf(v.z) | ((uint_t)f2bf(v.w) << 16);
                *(uint2*)&xs[r][q * 4] = u;
            }
        }
        #pragma unroll
        for (int i = 0; i < 2; i++) {
            int cq = t + i * 256;           // 0..511
            int c = cq >> 2, q = cq & 3;
            *(uint4*)&ws[c][q * 8] = wT16[(size_t)c * 16 + kt * 4 + q];
        }
        __syncthreads();

        bf16x8 aF[4], bF[4];
        #pragma unroll
        for (int nb = 0; nb < 4; nb++)
            aF[nb] = *(const bf16x8*)&xs[wrN * 64 + nb * 16 + ll][lh * 8];
        #pragma unroll
        for (int cb = 0; cb < 4; cb++)
            bF[cb] = *(const bf16x8*)&ws[wcC * 64 + cb * 16 + ll][lh * 8];
        #pragma unroll
        for (int cb = 0; cb < 4; cb++)
            #pragma unroll
            for (int nb = 0; nb < 4; nb++)
                acc[cb][nb] = __builtin_amdgcn_mfma_f32_16x16x32_bf16(
                                  bF[cb], aF[nb], acc[cb][nb], 0, 0, 0);
        __syncthreads();
    }

    // epilogue: lane -> node = wrN*64+nb*16+ll ; reg i -> col = wcC*64+cb*16+lh*4+i
    #pragma unroll
    for (int nb = 0; nb < 4; nb++) {
        int lr = wrN * 64 + nb * 16 + ll;
        int row = row0 + lr;
        if (full || row < N) {
            float s = ivs[lr];
            #pragma unroll
            for (int cb = 0; cb < 4; cb++) {
                f32x4 a = acc[cb][nb];
                uint2 u;
                u.x = (uint_t)f2bf(s * a.x) | ((uint_t)f2bf(s * a.y) << 16);
                u.y = (uint_t)f2bf(s * a.z) | ((uint_t)f2bf(s * a.w) << 16);
                int colb = wcC * 64 + cb * 16 + lh * 4;
                *(uint2*)(outg + (size_t)row * 128 + colb) = u;
            }
        }
    }
}

// ---------------- Aggregate (bf16 gather -> bf16 out) ----------------

__global__ __launch_bounds__(256) void k_agg(const ushort_t* __restrict__ g,
                            const int* __restrict__ rowptr,
                            const int* __restrict__ col, const float* __restrict__ inv_sqrt,
                            const float* __restrict__ bias, ushort_t* __restrict__ outh, int N) {
    int wid  = (blockIdx.x * blockDim.x + threadIdx.x) >> 6;   // node
    int lane = threadIdx.x & 63;
    if (wid >= N) return;

    int start = rowptr[wid];
    int end   = rowptr[wid + 1];

    const uint_t* g1 = (const uint_t*)g;    // row = 64 uints (128 bf16)
    float accx = 0.f, accy = 0.f;

    for (int tt = start; tt < end; tt += 8) {
        int idx[8];
        #pragma unroll
        for (int i = 0; i < 8; i++)
            idx[i] = (tt + i < end) ? col[tt + i] : wid;
        uint_t v[8];
        #pragma unroll
        for (int i = 0; i < 8; i++)
            v[i] = g1[(size_t)((unsigned)idx[i] * 64u + (unsigned)lane)];
        #pragma unroll
        for (int i = 0; i < 8; i++) {
            if (tt + i < end) {
                accx += bfl(v[i]);
                accy += bfh(v[i]);
            }
        }
    }

    uint_t sv = g1[(unsigned)wid * 64u + (unsigned)lane];
    accx += bfl(sv);
    accy += bfh(sv);

    float is = inv_sqrt[wid];
    float2 b = ((const float2*)bias)[lane];
    float ox = fmaxf(fmaf(is, accx, b.x), 0.f);
    float oy = fmaxf(fmaf(is, accy, b.y), 0.f);
    uint_t pk = (uint_t)f2bf(ox) | ((uint_t)f2bf(oy) << 16);
    ((uint_t*)outh)[(size_t)wid * 64 + lane] = pk;
}

// ---------------- Pool: parallel, wave = 16 rows, lane = feature pair ----------------

__global__ __launch_bounds__(256) void k_pool(const ushort_t* __restrict__ h,
                       const int* __restrict__ batch,
                       float* __restrict__ pooled, int* __restrict__ counts, int N) {
    int w    = threadIdx.x >> 6;          // wave 0..3
    int lane = threadIdx.x & 63;
    int row0 = blockIdx.x * 64 + w * 16;
    if (row0 >= N) return;
    int nr = N - row0; if (nr > 16) nr = 16;

    const uint_t* h1 = (const uint_t*)h;

    uint_t v[16];
    int    bb[16];
    #pragma unroll
    for (int i = 0; i < 16; i++) {
        int r = (i < nr) ? row0 + i : row0;
        v[i]  = h1[(size_t)r * 64 + lane];
        bb[i] = batch[r];
    }

    float ax = 0.f, ay = 0.f;
    int cnt = 0;
    int cur = bb[0];
    #pragma unroll
    for (int i = 0; i < 16; i++) {
        if (i < nr) {
            if (bb[i] != cur) {
                atomicAdd(&pooled[(size_t)cur * 128 + lane * 2],     ax);
                atomicAdd(&pooled[(size_t)cur * 128 + lane * 2 + 1], ay);
                if (lane == 0) atomicAdd(&counts[cur], cnt);
                ax = 0.f; ay = 0.f; cnt = 0; cur = bb[i];
            }
            ax += bfl(v[i]);
            ay += bfh(v[i]);
            cnt++;
        }
    }
    atomicAdd(&pooled[(size_t)cur * 128 + lane * 2],     ax);
    atomicAdd(&pooled[(size_t)cur * 128 + lane * 2 + 1], ay);
    if (lane == 0) atomicAdd(&counts[cur], cnt);
}

// ---------------- MLP head ----------------

__global__ void k_mlp(const float* __restrict__ pooled, const int* __restrict__ counts,
                      const float* __restrict__ Wc1, const float* __restrict__ bc1,
                      const float* __restrict__ Wc2, const float* __restrict__ bc2,
                      float* __restrict__ out, int G) {
    int g = blockIdx.x;
    int j = threadIdx.x;    // 0..63
    __shared__ float pm[128];
    __shared__ float z[64];

    float invc = 1.0f / fmaxf((float)counts[g], 1.0f);
    pm[j]      = pooled[(size_t)g * 128 + j] * invc;
    pm[j + 64] = pooled[(size_t)g * 128 + 64 + j] * invc;
    __syncthreads();

    float a = bc1[j];
    #pragma unroll 8
    for (int k = 0; k < 128; k++) a += pm[k] * Wc1[k * 64 + j];
    z[j] = fmaxf(a, 0.f);
    __syncthreads();

    if (j < 8) {
        float o = bc2[j];
        #pragma unroll 8
        for (int k = 0; k < 64; k++) o += z[k] * Wc2[k * 8 + j];
        out[(size_t)g * 8 + j] = o;
    }
}

// ---------------- launch ----------------

extern "C" void kernel_launch(void* const* d_in, const int* in_sizes, int n_in,
                              void* d_out, int out_size, void* d_ws, size_t ws_size,
                              hipStream_t stream) {
    const float* x    = (const float*)d_in[0];
    const int*   ei   = (const int*)d_in[1];
    const int*   batch= (const int*)d_in[2];
    const float* W1   = (const float*)d_in[4];
    const float* b1   = (const float*)d_in[5];
    const float* W2   = (const float*)d_in[6];
    const float* b2   = (const float*)d_in[7];
    const float* Wc1  = (const float*)d_in[8];
    const float* bc1  = (const float*)d_in[9];
    const float* Wc2  = (const float*)d_in[10];
    const float* bc2  = (const float*)d_in[11];
    float* out = (float*)d_out;

    const int N = in_sizes[0] / 128;
    const int E = in_sizes[1] / 2;
    const int G = out_size / 8;

    const int* src = ei;
    const int* dst = ei + E;

    const int NBK = DIV_UP(N, 256);     // buckets of 256 nodes
    const int NB1 = DIV_UP(E, CH);      // partition blocks

    char* p = (char*)d_ws;
    auto alloc = [&](size_t bytes) {
        char* q = p;
        p += (bytes + 255) & ~(size_t)255;
        return q;
    };
    ushort_t* bufG1    = (ushort_t*)alloc((size_t)N * 128 * 2);  // g1 / h2 (bf16)
    ushort_t* bufG2    = (ushort_t*)alloc((size_t)N * 128 * 2);  // g2 (bf16)
    ushort_t* bufH     = (ushort_t*)alloc((size_t)N * 128 * 2);  // h1 (bf16)
    int*      rowptr   = (int*)     alloc(((size_t)N + 1) * 4);
    int*      colA     = (int*)     alloc((size_t)E * 4);
    float*    inv_sqrt = (float*)   alloc((size_t)N * 4);
    int*      blk_hist = (int*)     alloc((size_t)NBK * NB1 * 4);
    int*      blk_off  = (int*)     alloc((size_t)NBK * NB1 * 4);
    int*      bkt_base = (int*)     alloc(((size_t)NBK + 1) * 4);
    int*      bktT     = (int*)     alloc((size_t)NBK * 4);
    ushort_t* wT1      = (ushort_t*)alloc(128 * 128 * 2);
    ushort_t* wT2      = (ushort_t*)alloc(128 * 128 * 2);
    float*    pooled   = (float*)   alloc((size_t)G * 128 * 4);
    int*      counts   = (int*)     alloc((size_t)G * 4);

    // part_arr aliases bufG1: consumed by k_sortfill before GEMM1 writes bufG1
    unsigned int* part_arr = (unsigned int*)bufG1;

    hipMemsetAsync(pooled, 0, (size_t)G * 128 * 4, stream);
    hipMemsetAsync(counts, 0, (size_t)G * 4, stream);

    // W prep (bf16 transpose) + CSR build
    k_prepW<<<128, 256, 0, stream>>>(W1, W2, wT1, wT2);
    k_hist1<<<NB1, 256, 0, stream>>>(dst, E, NBK, NB1, blk_hist);
    k_rowscan<<<NBK, 256, 0, stream>>>(blk_hist, blk_off, bktT, NB1);
    k_bktscan<<<1, 1024, 0, stream>>>(bktT, bkt_base, NBK, E);
    k_scatter1<<<NB1, 256, 0, stream>>>(src, dst, E, NBK, NB1, blk_off, bkt_base, part_arr);
    k_sortfill<<<NBK, 256, 0, stream>>>(part_arr, bkt_base, N, E, colA, rowptr, inv_sqrt);

    // layer 1: MFMA GEMM (f32 in) -> g1 bf16 ; aggregate -> h1 bf16
    k_gemm_mfma<false><<<DIV_UP(N, 128), 256, 0, stream>>>(x, wT1, inv_sqrt, bufG1, N);
    k_agg<<<DIV_UP(N, 4), 256, 0, stream>>>(bufG1, rowptr, colA, inv_sqrt, b1, bufH, N);

    // layer 2: MFMA GEMM (bf16 in) -> g2 bf16 ; aggregate -> h2 bf16 (reuse bufG1)
    k_gemm_mfma<true><<<DIV_UP(N, 128), 256, 0, stream>>>(bufH, wT2, inv_sqrt, bufG2, N);
    k_agg<<<DIV_UP(N, 4), 256, 0, stream>>>(bufG2, rowptr, colA, inv_sqrt, b2, bufG1, N);

    // pool + head
    k_pool<<<DIV_UP(N, 64), 256, 0, stream>>>(bufG1, batch, pooled, counts, N);
    k_mlp<<<G, 64, 0, stream>>>(pooled, counts, Wc1, bc1, Wc2, bc2, out, G);
}

// Round 14
// 283.477 us; speedup vs baseline: 1.3466x; 1.0464x over previous
//
#include <hip/hip_runtime.h>
#include <hip/hip_bf16.h>

#define DIV_UP(a,b) (((a)+(b)-1)/(b))

#define CH   9216    // edges per partition block
#define CAP  7424    // max edges per 256-node bucket in sortfill (mean 4096)

typedef unsigned short ushort_t;
typedef unsigned int   uint_t;
typedef __attribute__((ext_vector_type(8))) short bf16x8;   // 8 bf16 = 4 VGPR
typedef __attribute__((ext_vector_type(4))) float f32x4;

__device__ __forceinline__ ushort_t f2bf(float f) {
    __hip_bfloat16 h = __float2bfloat16(f);   // RNE
    ushort_t u;
    __builtin_memcpy(&u, &h, 2);
    return u;
}
__device__ __forceinline__ float bfl(uint_t u) { return __uint_as_float(u << 16); }
__device__ __forceinline__ float bfh(uint_t u) { return __uint_as_float(u & 0xffff0000u); }

// ---------------- CSR build: bucketed counting sort ----------------
// bucket = dst >> 8 (256 nodes per bucket)

__global__ __launch_bounds__(256) void k_hist1(const int* __restrict__ dst, int E,
                                               int NBK, int NB1,
                                               int* __restrict__ blk_hist) {
    __shared__ int hist[512];
    for (int i = threadIdx.x; i < NBK; i += 256) hist[i] = 0;
    __syncthreads();
    int base = blockIdx.x * CH;
    int lim = E - base; if (lim > CH) lim = CH;
    for (int i = threadIdx.x; i < lim; i += 256)
        atomicAdd(&hist[dst[base + i] >> 8], 1);
    __syncthreads();
    for (int b = threadIdx.x; b < NBK; b += 256)
        blk_hist[b * NB1 + blockIdx.x] = hist[b];   // bucket-major
}

// ---- parallel scan, level 1: per-bucket row scan (bucket-local) + totals ----
__global__ __launch_bounds__(256) void k_rowscan(const int* __restrict__ blk_hist,
                                                 int* __restrict__ blk_off,
                                                 int* __restrict__ T,
                                                 int NB1) {
    __shared__ int s[256];
    int b = blockIdx.x;
    const int* row = blk_hist + (size_t)b * NB1;
    int* orow = blk_off + (size_t)b * NB1;
    int t = threadIdx.x;
    int K = DIV_UP(NB1, 256);
    int lo = t * K;
    int hi = lo + K; if (hi > NB1) hi = NB1;
    int sum = 0;
    for (int i = lo; i < hi; i++) sum += row[i];
    s[t] = sum;
    __syncthreads();
    for (int o = 1; o < 256; o <<= 1) {
        int v = (t >= o) ? s[t - o] : 0;
        __syncthreads();
        s[t] += v;
        __syncthreads();
    }
    int run = s[t] - sum;   // exclusive prefix of this thread's chunk
    for (int i = lo; i < hi; i++) { orow[i] = run; run += row[i]; }
    if (t == 255) T[b] = s[255];
}

// ---- parallel scan, level 2: scan of bucket totals (tiny) ----
__global__ __launch_bounds__(1024) void k_bktscan(const int* __restrict__ T,
                                                  int* __restrict__ bkt_base,
                                                  int NBK, int E) {
    __shared__ int s[1024];
    int t = threadIdx.x;
    int K = DIV_UP(NBK, 1024);
    int lo = t * K;
    int hi = lo + K; if (hi > NBK) hi = NBK;
    int sum = 0;
    for (int i = lo; i < hi; i++) sum += T[i];
    s[t] = sum;
    __syncthreads();
    for (int o = 1; o < 1024; o <<= 1) {
        int v = (t >= o) ? s[t - o] : 0;
        __syncthreads();
        s[t] += v;
        __syncthreads();
    }
    int run = s[t] - sum;
    for (int i = lo; i < hi; i++) { bkt_base[i] = run; run += T[i]; }
    if (t == 0) bkt_base[NBK] = E;
}

// ---- scatter: group edges by bucket in LDS, copy out coalesced ----

__global__ __launch_bounds__(256) void k_scatter1(const int* __restrict__ src,
                                                  const int* __restrict__ dst, int E,
                                                  int NBK, int NB1,
                                                  const int* __restrict__ blk_off,
                                                  const int* __restrict__ bkt_base,
                                                  unsigned int* __restrict__ part_arr) {
    __shared__ unsigned int   stage[CH];
    __shared__ unsigned short bko[CH];
    __shared__ int hist[512];
    __shared__ int cur[512];
    __shared__ int off[512];

    int t = threadIdx.x;
    hist[t] = 0; hist[t + 256] = 0;
    __syncthreads();

    int base = blockIdx.x * CH;
    int lim = E - base; if (lim > CH) lim = CH;

    for (int i = t; i < lim; i += 256)
        atomicAdd(&hist[dst[base + i] >> 8], 1);
    __syncthreads();

    int c0 = hist[t], c1 = hist[t + 256];
    for (int o = 1; o < 512; o <<= 1) {
        int v0 = (t >= o) ? hist[t - o] : 0;
        int v1 = hist[t + 256 - o];
        __syncthreads();
        hist[t] += v0;
        hist[t + 256] += v1;
        __syncthreads();
    }
    int e0 = hist[t] - c0;          // exclusive
    int e1 = hist[t + 256] - c1;
    cur[t] = e0; cur[t + 256] = e1;
    if (t < NBK)       off[t]       = blk_off[t * NB1 + blockIdx.x] + bkt_base[t] - e0;
    if (t + 256 < NBK) off[t + 256] = blk_off[(t + 256) * NB1 + blockIdx.x] + bkt_base[t + 256] - e1;
    __syncthreads();

    for (int i = t; i < lim; i += 256) {
        int d = dst[base + i];
        int sv = src[base + i];
        int b = d >> 8;
        int slot = atomicAdd(&cur[b], 1);
        stage[slot] = ((unsigned int)sv << 8) | (unsigned int)(d & 255);
        bko[slot] = (unsigned short)b;
    }
    __syncthreads();

    for (int i = t; i < lim; i += 256) {
        int b = bko[i];
        part_arr[off[b] + i] = stage[i];
    }
}

__global__ __launch_bounds__(256) void k_sortfill(const unsigned int* __restrict__ part_arr,
                                                  const int* __restrict__ bkt_base,
                                                  int N, int E,
                                                  int* __restrict__ col,
                                                  int* __restrict__ rowptr,
                                                  float* __restrict__ inv_sqrt) {
    __shared__ unsigned int in_[CAP];
    __shared__ int outS[CAP];
    __shared__ int hist[256];
    __shared__ int scn[256];
    __shared__ int cur[256];

    int b = blockIdx.x;
    int base = bkt_base[b];
    int nb   = bkt_base[b + 1] - base;
    int t = threadIdx.x;

    hist[t] = 0;
    __syncthreads();

    for (int i = t; i < nb; i += 256) {
        unsigned int pk = part_arr[base + i];
        in_[i] = pk;
        atomicAdd(&hist[pk & 255u], 1);
    }
    __syncthreads();

    int cnt = hist[t];
    for (int o = 1; o < 256; o <<= 1) {
        int v = (t >= o) ? hist[t - o] : 0;
        __syncthreads();
        hist[t] += v;
        __syncthreads();
    }
    int excl = hist[t] - cnt;
    scn[t] = excl;
    cur[t] = 0;
    __syncthreads();

    for (int i = t; i < nb; i += 256) {
        unsigned int pk = in_[i];
        int d = (int)(pk & 255u);
        int r = atomicAdd(&cur[d], 1);
        outS[scn[d] + r] = (int)(pk >> 8);
    }
    __syncthreads();

    for (int i = t; i < nb; i += 256) col[base + i] = outS[i];

    int node = b * 256 + t;
    if (node < N) {
        rowptr[node] = base + excl;
        inv_sqrt[node] = rsqrtf((float)(cnt + 1));   // +1: self-loop
    }
    if (b == 0 && t == 0) rowptr[N] = E;
}

// ---------------- W prep: wT[c][k] = bf16(W[k][c]) for both layers ----------------

__global__ __launch_bounds__(256) void k_prepW(const float* __restrict__ W1,
                                               const float* __restrict__ W2,
                                               ushort_t* __restrict__ wT1,
                                               ushort_t* __restrict__ wT2) {
    int idx = blockIdx.x * 256 + threadIdx.x;   // grid 128 blocks = 32768
    const float* W = (idx < 16384) ? W1 : W2;
    ushort_t*    O = (idx < 16384) ? wT1 : wT2;
    int j = idx & 16383;
    int k = j >> 7, c = j & 127;
    O[c * 128 + k] = f2bf(W[j]);
}

// ---------------- MFMA GEMM: outg[n][c] = bf16(inv_sqrt[n] * (X @ W)[n][c]) ----------------

template <bool BF16IN>
__global__ __launch_bounds__(256) void k_gemm_mfma(const void* __restrict__ inp,
                        const ushort_t* __restrict__ wT,   // [128 c][128 k] bf16
                        const float* __restrict__ inv_sqrt,
                        ushort_t* __restrict__ outg, int N) {
    __shared__ ushort_t xs[128][56];   // [node][k]
    __shared__ ushort_t ws[128][56];   // [col][k]
    __shared__ float ivs[128];

    const int t = threadIdx.x;
    const int row0 = blockIdx.x * 128;
    const int lane = t & 63;
    const int wv = t >> 6;
    const int wrN = wv >> 1;        // node quadrant *64
    const int wcC = wv & 1;         // col quadrant *64
    const int lh = lane >> 4;       // 0..3
    const int ll = lane & 15;

    const bool full = (row0 + 128 <= N);

    if (t < 128) {
        int r = row0 + t;
        ivs[t] = inv_sqrt[(full || r < N) ? r : 0];
    }

    f32x4 acc[4][4];   // [cb][nb]
    #pragma unroll
    for (int a = 0; a < 4; a++)
        #pragma unroll
        for (int b = 0; b < 4; b++)
            acc[a][b] = (f32x4){0.f, 0.f, 0.f, 0.f};

    const uint4* wT16 = (const uint4*)wT;   // row = 16 uint4

    for (int kt = 0; kt < 4; kt++) {
        if (BF16IN) {
            const uint4* in16 = (const uint4*)inp;
            #pragma unroll
            for (int i = 0; i < 2; i++) {
                int fq = t + i * 256;       // 0..511
                int r = fq >> 2, q = fq & 3;
                int row = row0 + r;
                uint4 v = make_uint4(0u, 0u, 0u, 0u);
                if (full || row < N) v = in16[(size_t)row * 16 + kt * 4 + q];
                *(uint4*)&xs[r][q * 8] = v;
            }
        } else {
            const float4* in4 = (const float4*)inp;
            #pragma unroll
            for (int i = 0; i < 4; i++) {
                int fq = t + i * 256;       // 0..1023
                int r = fq >> 3, q = fq & 7;
                int row = row0 + r;
                float4 v = make_float4(0.f, 0.f, 0.f, 0.f);
                if (full || row < N) v = in4[(size_t)row * 32 + kt * 8 + q];
                uint2 u;
                u.x = (uint_t)f2bf(v.x) | ((uint_t)f2bf(v.y) << 16);
                u.y = (uint_t)f2bf(v.z) | ((uint_t)f2bf(v.w) << 16);
                *(uint2*)&xs[r][q * 4] = u;
            }
        }
        #pragma unroll
        for (int i = 0; i < 2; i++) {
            int cq = t + i * 256;           // 0..511
            int c = cq >> 2, q = cq & 3;
            *(uint4*)&ws[c][q * 8] = wT16[(size_t)c * 16 + kt * 4 + q];
        }
        __syncthreads();

        bf16x8 aF[4], bF[4];
        #pragma unroll
        for (int nb = 0; nb < 4; nb++)
            aF[nb] = *(const bf16x8*)&xs[wrN * 64 + nb * 16 + ll][lh * 8];
        #pragma unroll
        for (int cb = 0; cb < 4; cb++)
            bF[cb] = *(const bf16x8*)&ws[wcC * 64 + cb * 16 + ll][lh * 8];
        #pragma unroll
        for (int cb = 0; cb < 4; cb++)
            #pragma unroll
            for (int nb = 0; nb < 4; nb++)
                acc[cb][nb] = __builtin_amdgcn_mfma_f32_16x16x32_bf16(
                                  bF[cb], aF[nb], acc[cb][nb], 0, 0, 0);
        __syncthreads();
    }

    #pragma unroll
    for (int nb = 0; nb < 4; nb++) {
        int lr = wrN * 64 + nb * 16 + ll;
        int row = row0 + lr;
        if (full || row < N) {
            float s = ivs[lr];
            #pragma unroll
            for (int cb = 0; cb < 4; cb++) {
                f32x4 a = acc[cb][nb];
                uint2 u;
                u.x = (uint_t)f2bf(s * a.x) | ((uint_t)f2bf(s * a.y) << 16);
                u.y = (uint_t)f2bf(s * a.z) | ((uint_t)f2bf(s * a.w) << 16);
                int colb = wcC * 64 + cb * 16 + lh * 4;
                *(uint2*)(outg + (size_t)row * 128 + colb) = u;
            }
        }
    }
}

// ---------------- Aggregate (bf16 gather -> bf16 out), 16 edges in flight ----------------
// h[n] = relu(inv_sqrt[n]*(sum g[col] + g[n]) + b), stored packed bf16.
// One wave per node; unroll 16 covers the mean degree in one issue burst.
// Dummy (beyond-degree) loads hit the self row (cache-hot).

__global__ __launch_bounds__(256) void k_agg(const ushort_t* __restrict__ g,
                            const int* __restrict__ rowptr,
                            const int* __restrict__ col, const float* __restrict__ inv_sqrt,
                            const float* __restrict__ bias, ushort_t* __restrict__ outh, int N) {
    int wid  = (blockIdx.x * blockDim.x + threadIdx.x) >> 6;   // node
    int lane = threadIdx.x & 63;
    if (wid >= N) return;

    int start = rowptr[wid];
    int end   = rowptr[wid + 1];

    const uint_t* g1 = (const uint_t*)g;    // row = 64 uints (128 bf16)
    float accx = 0.f, accy = 0.f;

    for (int tt = start; tt < end; tt += 16) {
        int idx[16];
        #pragma unroll
        for (int i = 0; i < 16; i++)
            idx[i] = (tt + i < end) ? col[tt + i] : wid;
        uint_t v[16];
        #pragma unroll
        for (int i = 0; i < 16; i++)
            v[i] = g1[(size_t)((unsigned)idx[i] * 64u + (unsigned)lane)];
        #pragma unroll
        for (int i = 0; i < 16; i++) {
            if (tt + i < end) {
                accx += bfl(v[i]);
                accy += bfh(v[i]);
            }
        }
    }

    uint_t sv = g1[(unsigned)wid * 64u + (unsigned)lane];
    accx += bfl(sv);
    accy += bfh(sv);

    float is = inv_sqrt[wid];
    float2 b = ((const float2*)bias)[lane];
    float ox = fmaxf(fmaf(is, accx, b.x), 0.f);
    float oy = fmaxf(fmaf(is, accy, b.y), 0.f);
    uint_t pk = (uint_t)f2bf(ox) | ((uint_t)f2bf(oy) << 16);
    ((uint_t*)outh)[(size_t)wid * 64 + lane] = pk;
}

// ---------------- Pool: parallel, wave = 16 rows, lane = feature pair ----------------

__global__ __launch_bounds__(256) void k_pool(const ushort_t* __restrict__ h,
                       const int* __restrict__ batch,
                       float* __restrict__ pooled, int* __restrict__ counts, int N) {
    int w    = threadIdx.x >> 6;          // wave 0..3
    int lane = threadIdx.x & 63;
    int row0 = blockIdx.x * 64 + w * 16;
    if (row0 >= N) return;
    int nr = N - row0; if (nr > 16) nr = 16;

    const uint_t* h1 = (const uint_t*)h;

    uint_t v[16];
    int    bb[16];
    #pragma unroll
    for (int i = 0; i < 16; i++) {
        int r = (i < nr) ? row0 + i : row0;
        v[i]  = h1[(size_t)r * 64 + lane];
        bb[i] = batch[r];
    }

    float ax = 0.f, ay = 0.f;
    int cnt = 0;
    int cur = bb[0];
    #pragma unroll
    for (int i = 0; i < 16; i++) {
        if (i < nr) {
            if (bb[i] != cur) {
                atomicAdd(&pooled[(size_t)cur * 128 + lane * 2],     ax);
                atomicAdd(&pooled[(size_t)cur * 128 + lane * 2 + 1], ay);
                if (lane == 0) atomicAdd(&counts[cur], cnt);
                ax = 0.f; ay = 0.f; cnt = 0; cur = bb[i];
            }
            ax += bfl(v[i]);
            ay += bfh(v[i]);
            cnt++;
        }
    }
    atomicAdd(&pooled[(size_t)cur * 128 + lane * 2],     ax);
    atomicAdd(&pooled[(size_t)cur * 128 + lane * 2 + 1], ay);
    if (lane == 0) atomicAdd(&counts[cur], cnt);
}

// ---------------- MLP head ----------------

__global__ void k_mlp(const float* __restrict__ pooled, const int* __restrict__ counts,
                      const float* __restrict__ Wc1, const float* __restrict__ bc1,
                      const float* __restrict__ Wc2, const float* __restrict__ bc2,
                      float* __restrict__ out, int G) {
    int g = blockIdx.x;
    int j = threadIdx.x;    // 0..63
    __shared__ float pm[128];
    __shared__ float z[64];

    float invc = 1.0f / fmaxf((float)counts[g], 1.0f);
    pm[j]      = pooled[(size_t)g * 128 + j] * invc;
    pm[j + 64] = pooled[(size_t)g * 128 + 64 + j] * invc;
    __syncthreads();

    float a = bc1[j];
    #pragma unroll 8
    for (int k = 0; k < 128; k++) a += pm[k] * Wc1[k * 64 + j];
    z[j] = fmaxf(a, 0.f);
    __syncthreads();

    if (j < 8) {
        float o = bc2[j];
        #pragma unroll 8
        for (int k = 0; k < 64; k++) o += z[k] * Wc2[k * 8 + j];
        out[(size_t)g * 8 + j] = o;
    }
}

// ---------------- launch ----------------

extern "C" void kernel_launch(void* const* d_in, const int* in_sizes, int n_in,
                              void* d_out, int out_size, void* d_ws, size_t ws_size,
                              hipStream_t stream) {
    const float* x    = (const float*)d_in[0];
    const int*   ei   = (const int*)d_in[1];
    const int*   batch= (const int*)d_in[2];
    const float* W1   = (const float*)d_in[4];
    const float* b1   = (const float*)d_in[5];
    const float* W2   = (const float*)d_in[6];
    const float* b2   = (const float*)d_in[7];
    const float* Wc1  = (const float*)d_in[8];
    const float* bc1  = (const float*)d_in[9];
    const float* Wc2  = (const float*)d_in[10];
    const float* bc2  = (const float*)d_in[11];
    float* out = (float*)d_out;

    const int N = in_sizes[0] / 128;
    const int E = in_sizes[1] / 2;
    const int G = out_size / 8;

    const int* src = ei;
    const int* dst = ei + E;

    const int NBK = DIV_UP(N, 256);     // buckets of 256 nodes
    const int NB1 = DIV_UP(E, CH);      // partition blocks

    char* p = (char*)d_ws;
    auto alloc = [&](size_t bytes) {
        char* q = p;
        p += (bytes + 255) & ~(size_t)255;
        return q;
    };
    ushort_t* bufG1    = (ushort_t*)alloc((size_t)N * 128 * 2);  // g1 / h2 (bf16)
    ushort_t* bufG2    = (ushort_t*)alloc((size_t)N * 128 * 2);  // g2 (bf16)
    ushort_t* bufH     = (ushort_t*)alloc((size_t)N * 128 * 2);  // h1 (bf16)
    int*      rowptr   = (int*)     alloc(((size_t)N + 1) * 4);
    int*      colA     = (int*)     alloc((size_t)E * 4);
    float*    inv_sqrt = (float*)   alloc((size_t)N * 4);
    int*      blk_hist = (int*)     alloc((size_t)NBK * NB1 * 4);
    int*      blk_off  = (int*)     alloc((size_t)NBK * NB1 * 4);
    int*      bkt_base = (int*)     alloc(((size_t)NBK + 1) * 4);
    int*      bktT     = (int*)     alloc((size_t)NBK * 4);
    ushort_t* wT1      = (ushort_t*)alloc(128 * 128 * 2);
    ushort_t* wT2      = (ushort_t*)alloc(128 * 128 * 2);
    float*    pooled   = (float*)   alloc((size_t)G * 128 * 4);
    int*      counts   = (int*)     alloc((size_t)G * 4);

    // part_arr aliases bufG1: consumed by k_sortfill before GEMM1 writes bufG1
    unsigned int* part_arr = (unsigned int*)bufG1;

    hipMemsetAsync(pooled, 0, (size_t)G * 128 * 4, stream);
    hipMemsetAsync(counts, 0, (size_t)G * 4, stream);

    // W prep (bf16 transpose) + CSR build
    k_prepW<<<128, 256, 0, stream>>>(W1, W2, wT1, wT2);
    k_hist1<<<NB1, 256, 0, stream>>>(dst, E, NBK, NB1, blk_hist);
    k_rowscan<<<NBK, 256, 0, stream>>>(blk_hist, blk_off, bktT, NB1);
    k_bktscan<<<1, 1024, 0, stream>>>(bktT, bkt_base, NBK, E);
    k_scatter1<<<NB1, 256, 0, stream>>>(src, dst, E, NBK, NB1, blk_off, bkt_base, part_arr);
    k_sortfill<<<NBK, 256, 0, stream>>>(part_arr, bkt_base, N, E, colA, rowptr, inv_sqrt);

    // layer 1: MFMA GEMM (f32 in) -> g1 bf16 ; aggregate -> h1 bf16
    k_gemm_mfma<false><<<DIV_UP(N, 128), 256, 0, stream>>>(x, wT1, inv_sqrt, bufG1, N);
    k_agg<<<DIV_UP(N, 4), 256, 0, stream>>>(bufG1, rowptr, colA, inv_sqrt, b1, bufH, N);

    // layer 2: MFMA GEMM (bf16 in) -> g2 bf16 ; aggregate -> h2 bf16 (reuse bufG1)
    k_gemm_mfma<true><<<DIV_UP(N, 128), 256, 0, stream>>>(bufH, wT2, inv_sqrt, bufG2, N);
    k_agg<<<DIV_UP(N, 4), 256, 0, stream>>>(bufG2, rowptr, colA, inv_sqrt, b2, bufG1, N);

    // pool + head
    k_pool<<<DIV_UP(N, 64), 256, 0, stream>>>(bufG1, batch, pooled, counts, N);
    k_mlp<<<G, 64, 0, stream>>>(pooled, counts, Wc1, bc1, Wc2, bc2, out, G);
}

// Round 15
// 276.593 us; speedup vs baseline: 1.3802x; 1.0249x over previous
//
#include <hip/hip_runtime.h>
#include <hip/hip_bf16.h>

#define DIV_UP(a,b) (((a)+(b)-1)/(b))

#define CH   9216    // edges per partition block
#define CAP  7424    // max edges per 256-node bucket in sortfill (mean 4096)

typedef unsigned short ushort_t;
typedef unsigned int   uint_t;
typedef __attribute__((ext_vector_type(8))) short bf16x8;   // 8 bf16 = 4 VGPR
typedef __attribute__((ext_vector_type(4))) float f32x4;

__device__ __forceinline__ ushort_t f2bf(float f) {
    __hip_bfloat16 h = __float2bfloat16(f);   // RNE
    ushort_t u;
    __builtin_memcpy(&u, &h, 2);
    return u;
}
__device__ __forceinline__ float bfl(uint_t u) { return __uint_as_float(u << 16); }
__device__ __forceinline__ float bfh(uint_t u) { return __uint_as_float(u & 0xffff0000u); }

// ---------------- Setup: W transpose->bf16, zero pooled/counts, zero rows, done flag ----------------
// blocks 0..127: prepW ; 128..159: zero pooled ; 160: counts + zero-rows + done

__global__ __launch_bounds__(256) void k_setup(const float* __restrict__ W1,
                                               const float* __restrict__ W2,
                                               ushort_t* __restrict__ wT1,
                                               ushort_t* __restrict__ wT2,
                                               float* __restrict__ pooled,
                                               int* __restrict__ counts, int G,
                                               ushort_t* __restrict__ zrow1,
                                               ushort_t* __restrict__ zrow2,
                                               int* __restrict__ done) {
    int b = blockIdx.x;
    int t = threadIdx.x;
    if (b < 128) {
        int idx = b * 256 + t;
        const float* W = (idx < 16384) ? W1 : W2;
        ushort_t*    O = (idx < 16384) ? wT1 : wT2;
        int j = idx & 16383;
        int k = j >> 7, c = j & 127;
        O[c * 128 + k] = f2bf(W[j]);
    } else if (b < 160) {
        int i = (b - 128) * 256 + t;
        if (i < G * 128) pooled[i] = 0.f;
    } else {
        if (t < 128) { zrow1[t] = 0; zrow2[t] = 0; }
        else if (t < 256) { zrow1[t - 128 + 128 - 128 + 128] = 0; zrow2[t] = 0; }
        // (rows are 128 wide; the above covers t<128 for both; redundant writes for 128<=t<256 clamped:)
        for (int i = t; i < G; i += 256) counts[i] = 0;
        if (t == 0) *done = 0;
    }
}

// ---------------- CSR build: bucketed counting sort ----------------
// bucket = dst >> 8 (256 nodes per bucket)

__global__ __launch_bounds__(256) void k_hist1(const int* __restrict__ dst, int E,
                                               int NBK, int NB1,
                                               int* __restrict__ blk_hist) {
    __shared__ int hist[512];
    for (int i = threadIdx.x; i < NBK; i += 256) hist[i] = 0;
    __syncthreads();
    int base = blockIdx.x * CH;
    int lim = E - base; if (lim > CH) lim = CH;
    for (int i = threadIdx.x; i < lim; i += 256)
        atomicAdd(&hist[dst[base + i] >> 8], 1);
    __syncthreads();
    for (int b = threadIdx.x; b < NBK; b += 256)
        blk_hist[b * NB1 + blockIdx.x] = hist[b];   // bucket-major
}

// ---- row scan + (last block) bucket-total scan, fused via done-counter ----

__global__ __launch_bounds__(256) void k_rowscan(const int* __restrict__ blk_hist,
                                                 int* __restrict__ blk_off,
                                                 int* __restrict__ T,
                                                 int* __restrict__ bkt_base,
                                                 int* __restrict__ done,
                                                 int NBK, int NB1, int E) {
    __shared__ int s[256];
    __shared__ int amLast;
    int b = blockIdx.x;
    const int* row = blk_hist + (size_t)b * NB1;
    int* orow = blk_off + (size_t)b * NB1;
    int t = threadIdx.x;
    int K = DIV_UP(NB1, 256);
    int lo = t * K;
    int hi = lo + K; if (hi > NB1) hi = NB1;
    int sum = 0;
    for (int i = lo; i < hi; i++) sum += row[i];
    s[t] = sum;
    __syncthreads();
    for (int o = 1; o < 256; o <<= 1) {
        int v = (t >= o) ? s[t - o] : 0;
        __syncthreads();
        s[t] += v;
        __syncthreads();
    }
    int run = s[t] - sum;   // exclusive prefix of this thread's chunk
    for (int i = lo; i < hi; i++) { orow[i] = run; run += row[i]; }
    if (t == 255) atomicExch(&T[b], s[255]);    // device-coherent publish
    __syncthreads();
    if (t == 0) amLast = (atomicAdd(done, 1) == NBK - 1);
    __syncthreads();
    if (!amLast) return;

    // last block: scan bucket totals -> bkt_base (atomic reads for coherence)
    int K2 = DIV_UP(NBK, 256);          // <=8 for N <= 512K
    int lo2 = t * K2;
    int hi2 = lo2 + K2; if (hi2 > NBK) hi2 = NBK;
    int tv[8];
    int sum2 = 0;
    for (int i = lo2, j = 0; i < hi2; i++, j++) { tv[j] = atomicAdd(&T[i], 0); sum2 += tv[j]; }
    s[t] = sum2;
    __syncthreads();
    for (int o = 1; o < 256; o <<= 1) {
        int v = (t >= o) ? s[t - o] : 0;
        __syncthreads();
        s[t] += v;
        __syncthreads();
    }
    int run2 = s[t] - sum2;
    for (int i = lo2, j = 0; i < hi2; i++, j++) { bkt_base[i] = run2; run2 += tv[j]; }
    if (t == 0) bkt_base[NBK] = E;
}

// ---- scatter: group edges by bucket in LDS, copy out coalesced ----

__global__ __launch_bounds__(256) void k_scatter1(const int* __restrict__ src,
                                                  const int* __restrict__ dst, int E,
                                                  int NBK, int NB1,
                                                  const int* __restrict__ blk_off,
                                                  const int* __restrict__ bkt_base,
                                                  unsigned int* __restrict__ part_arr) {
    __shared__ unsigned int   stage[CH];
    __shared__ unsigned short bko[CH];
    __shared__ int hist[512];
    __shared__ int cur[512];
    __shared__ int off[512];

    int t = threadIdx.x;
    hist[t] = 0; hist[t + 256] = 0;
    __syncthreads();

    int base = blockIdx.x * CH;
    int lim = E - base; if (lim > CH) lim = CH;

    for (int i = t; i < lim; i += 256)
        atomicAdd(&hist[dst[base + i] >> 8], 1);
    __syncthreads();

    int c0 = hist[t], c1 = hist[t + 256];
    for (int o = 1; o < 512; o <<= 1) {
        int v0 = (t >= o) ? hist[t - o] : 0;
        int v1 = hist[t + 256 - o];
        __syncthreads();
        hist[t] += v0;
        hist[t + 256] += v1;
        __syncthreads();
    }
    int e0 = hist[t] - c0;          // exclusive
    int e1 = hist[t + 256] - c1;
    cur[t] = e0; cur[t + 256] = e1;
    if (t < NBK)       off[t]       = blk_off[t * NB1 + blockIdx.x] + bkt_base[t] - e0;
    if (t + 256 < NBK) off[t + 256] = blk_off[(t + 256) * NB1 + blockIdx.x] + bkt_base[t + 256] - e1;
    __syncthreads();

    for (int i = t; i < lim; i += 256) {
        int d = dst[base + i];
        int sv = src[base + i];
        int b = d >> 8;
        int slot = atomicAdd(&cur[b], 1);
        stage[slot] = ((unsigned int)sv << 8) | (unsigned int)(d & 255);
        bko[slot] = (unsigned short)b;
    }
    __syncthreads();

    for (int i = t; i < lim; i += 256) {
        int b = bko[i];
        part_arr[off[b] + i] = stage[i];
    }
}

__global__ __launch_bounds__(256) void k_sortfill(const unsigned int* __restrict__ part_arr,
                                                  const int* __restrict__ bkt_base,
                                                  int N, int E,
                                                  int* __restrict__ col,
                                                  int* __restrict__ rowptr,
                                                  float* __restrict__ inv_sqrt) {
    __shared__ unsigned int in_[CAP];
    __shared__ int outS[CAP];
    __shared__ int hist[256];
    __shared__ int scn[256];
    __shared__ int cur[256];

    int b = blockIdx.x;
    int base = bkt_base[b];
    int nb   = bkt_base[b + 1] - base;
    int t = threadIdx.x;

    hist[t] = 0;
    __syncthreads();

    for (int i = t; i < nb; i += 256) {
        unsigned int pk = part_arr[base + i];
        in_[i] = pk;
        atomicAdd(&hist[pk & 255u], 1);
    }
    __syncthreads();

    int cnt = hist[t];
    for (int o = 1; o < 256; o <<= 1) {
        int v = (t >= o) ? hist[t - o] : 0;
        __syncthreads();
        hist[t] += v;
        __syncthreads();
    }
    int excl = hist[t] - cnt;
    scn[t] = excl;
    cur[t] = 0;
    __syncthreads();

    for (int i = t; i < nb; i += 256) {
        unsigned int pk = in_[i];
        int d = (int)(pk & 255u);
        int r = atomicAdd(&cur[d], 1);
        outS[scn[d] + r] = (int)(pk >> 8);
    }
    __syncthreads();

    for (int i = t; i < nb; i += 256) col[base + i] = outS[i];

    int node = b * 256 + t;
    if (node < N) {
        rowptr[node] = base + excl;
        inv_sqrt[node] = rsqrtf((float)(cnt + 1));   // +1: self-loop
    }
    if (b == 0 && t == 0) rowptr[N] = E;
}

// ---------------- MFMA GEMM: outg[n][c] = bf16(inv_sqrt[n] * (X @ W)[n][c]) ----------------

template <bool BF16IN>
__global__ __launch_bounds__(256) void k_gemm_mfma(const void* __restrict__ inp,
                        const ushort_t* __restrict__ wT,   // [128 c][128 k] bf16
                        const float* __restrict__ inv_sqrt,
                        ushort_t* __restrict__ outg, int N) {
    __shared__ ushort_t xs[128][56];   // [node][k]
    __shared__ ushort_t ws[128][56];   // [col][k]
    __shared__ float ivs[128];

    const int t = threadIdx.x;
    const int row0 = blockIdx.x * 128;
    const int lane = t & 63;
    const int wv = t >> 6;
    const int wrN = wv >> 1;        // node quadrant *64
    const int wcC = wv & 1;         // col quadrant *64
    const int lh = lane >> 4;       // 0..3
    const int ll = lane & 15;

    const bool full = (row0 + 128 <= N);

    if (t < 128) {
        int r = row0 + t;
        ivs[t] = inv_sqrt[(full || r < N) ? r : 0];
    }

    f32x4 acc[4][4];   // [cb][nb]
    #pragma unroll
    for (int a = 0; a < 4; a++)
        #pragma unroll
        for (int b = 0; b < 4; b++)
            acc[a][b] = (f32x4){0.f, 0.f, 0.f, 0.f};

    const uint4* wT16 = (const uint4*)wT;   // row = 16 uint4

    for (int kt = 0; kt < 4; kt++) {
        if (BF16IN) {
            const uint4* in16 = (const uint4*)inp;
            #pragma unroll
            for (int i = 0; i < 2; i++) {
                int fq = t + i * 256;       // 0..511
                int r = fq >> 2, q = fq & 3;
                int row = row0 + r;
                uint4 v = make_uint4(0u, 0u, 0u, 0u);
                if (full || row < N) v = in16[(size_t)row * 16 + kt * 4 + q];
                *(uint4*)&xs[r][q * 8] = v;
            }
        } else {
            const float4* in4 = (const float4*)inp;
            #pragma unroll
            for (int i = 0; i < 4; i++) {
                int fq = t + i * 256;       // 0..1023
                int r = fq >> 3, q = fq & 7;
                int row = row0 + r;
                float4 v = make_float4(0.f, 0.f, 0.f, 0.f);
                if (full || row < N) v = in4[(size_t)row * 32 + kt * 8 + q];
                uint2 u;
                u.x = (uint_t)f2bf(v.x) | ((uint_t)f2bf(v.y) << 16);
                u.y = (uint_t)f2bf(v.z) | ((uint_t)f2bf(v.w) << 16);
                *(uint2*)&xs[r][q * 4] = u;
            }
        }
        #pragma unroll
        for (int i = 0; i < 2; i++) {
            int cq = t + i * 256;           // 0..511
            int c = cq >> 2, q = cq & 3;
            *(uint4*)&ws[c][q * 8] = wT16[(size_t)c * 16 + kt * 4 + q];
        }
        __syncthreads();

        bf16x8 aF[4], bF[4];
        #pragma unroll
        for (int nb = 0; nb < 4; nb++)
            aF[nb] = *(const bf16x8*)&xs[wrN * 64 + nb * 16 + ll][lh * 8];
        #pragma unroll
        for (int cb = 0; cb < 4; cb++)
            bF[cb] = *(const bf16x8*)&ws[wcC * 64 + cb * 16 + ll][lh * 8];
        #pragma unroll
        for (int cb = 0; cb < 4; cb++)
            #pragma unroll
            for (int nb = 0; nb < 4; nb++)
                acc[cb][nb] = __builtin_amdgcn_mfma_f32_16x16x32_bf16(
                                  bF[cb], aF[nb], acc[cb][nb], 0, 0, 0);
        __syncthreads();
    }

    #pragma unroll
    for (int nb = 0; nb < 4; nb++) {
        int lr = wrN * 64 + nb * 16 + ll;
        int row = row0 + lr;
        if (full || row < N) {
            float s = ivs[lr];
            #pragma unroll
            for (int cb = 0; cb < 4; cb++) {
                f32x4 a = acc[cb][nb];
                uint2 u;
                u.x = (uint_t)f2bf(s * a.x) | ((uint_t)f2bf(s * a.y) << 16);
                u.y = (uint_t)f2bf(s * a.z) | ((uint_t)f2bf(s * a.w) << 16);
                int colb = wcC * 64 + cb * 16 + lh * 4;
                *(uint2*)(outg + (size_t)row * 128 + colb) = u;
            }
        }
    }
}

// ---------------- Aggregate: zero-row dummies, unconditional accumulate ----------------
// h[n] = relu(inv_sqrt[n]*(sum g[col] + g[n]) + b), packed bf16 out.
// One wave per node, 16 gathers in flight; dummy idx -> row N (all zeros).

__global__ __launch_bounds__(256) void k_agg(const ushort_t* __restrict__ g,
                            const int* __restrict__ rowptr,
                            const int* __restrict__ col, const float* __restrict__ inv_sqrt,
                            const float* __restrict__ bias, ushort_t* __restrict__ outh, int N) {
    int wid  = (blockIdx.x * blockDim.x + threadIdx.x) >> 6;   // node
    int lane = threadIdx.x & 63;
    if (wid >= N) return;

    int start = rowptr[wid];
    int end   = rowptr[wid + 1];

    const uint_t* g1 = (const uint_t*)g;    // row = 64 uints (128 bf16)
    float accx = 0.f, accy = 0.f;

    for (int tt = start; tt < end; tt += 16) {
        int idx[16];
        #pragma unroll
        for (int i = 0; i < 16; i++)
            idx[i] = (tt + i < end) ? col[tt + i] : N;   // N = zero row
        uint_t v[16];
        #pragma unroll
        for (int i = 0; i < 16; i++)
            v[i] = g1[(size_t)((unsigned)idx[i] * 64u + (unsigned)lane)];
        #pragma unroll
        for (int i = 0; i < 16; i++) {
            accx += bfl(v[i]);
            accy += bfh(v[i]);
        }
    }

    uint_t sv = g1[(unsigned)wid * 64u + (unsigned)lane];
    accx += bfl(sv);
    accy += bfh(sv);

    float is = inv_sqrt[wid];
    float2 b = ((const float2*)bias)[lane];
    float ox = fmaxf(fmaf(is, accx, b.x), 0.f);
    float oy = fmaxf(fmaf(is, accy, b.y), 0.f);
    uint_t pk = (uint_t)f2bf(ox) | ((uint_t)f2bf(oy) << 16);
    ((uint_t*)outh)[(size_t)wid * 64 + lane] = pk;
}

// ---------------- Pool: parallel, wave = 16 rows, lane = feature pair ----------------

__global__ __launch_bounds__(256) void k_pool(const ushort_t* __restrict__ h,
                       const int* __restrict__ batch,
                       float* __restrict__ pooled, int* __restrict__ counts, int N) {
    int w    = threadIdx.x >> 6;          // wave 0..3
    int lane = threadIdx.x & 63;
    int row0 = blockIdx.x * 64 + w * 16;
    if (row0 >= N) return;
    int nr = N - row0; if (nr > 16) nr = 16;

    const uint_t* h1 = (const uint_t*)h;

    uint_t v[16];
    int    bb[16];
    #pragma unroll
    for (int i = 0; i < 16; i++) {
        int r = (i < nr) ? row0 + i : row0;
        v[i]  = h1[(size_t)r * 64 + lane];
        bb[i] = batch[r];
    }

    float ax = 0.f, ay = 0.f;
    int cnt = 0;
    int cur = bb[0];
    #pragma unroll
    for (int i = 0; i < 16; i++) {
        if (i < nr) {
            if (bb[i] != cur) {
                atomicAdd(&pooled[(size_t)cur * 128 + lane * 2],     ax);
                atomicAdd(&pooled[(size_t)cur * 128 + lane * 2 + 1], ay);
                if (lane == 0) atomicAdd(&counts[cur], cnt);
                ax = 0.f; ay = 0.f; cnt = 0; cur = bb[i];
            }
            ax += bfl(v[i]);
            ay += bfh(v[i]);
            cnt++;
        }
    }
    atomicAdd(&pooled[(size_t)cur * 128 + lane * 2],     ax);
    atomicAdd(&pooled[(size_t)cur * 128 + lane * 2 + 1], ay);
    if (lane == 0) atomicAdd(&counts[cur], cnt);
}

// ---------------- MLP head ----------------

__global__ void k_mlp(const float* __restrict__ pooled, const int* __restrict__ counts,
                      const float* __restrict__ Wc1, const float* __restrict__ bc1,
                      const float* __restrict__ Wc2, const float* __restrict__ bc2,
                      float* __restrict__ out, int G) {
    int g = blockIdx.x;
    int j = threadIdx.x;    // 0..63
    __shared__ float pm[128];
    __shared__ float z[64];

    float invc = 1.0f / fmaxf((float)counts[g], 1.0f);
    pm[j]      = pooled[(size_t)g * 128 + j] * invc;
    pm[j + 64] = pooled[(size_t)g * 128 + 64 + j] * invc;
    __syncthreads();

    float a = bc1[j];
    #pragma unroll 8
    for (int k = 0; k < 128; k++) a += pm[k] * Wc1[k * 64 + j];
    z[j] = fmaxf(a, 0.f);
    __syncthreads();

    if (j < 8) {
        float o = bc2[j];
        #pragma unroll 8
        for (int k = 0; k < 64; k++) o += z[k] * Wc2[k * 8 + j];
        out[(size_t)g * 8 + j] = o;
    }
}

// ---------------- launch ----------------

extern "C" void kernel_launch(void* const* d_in, const int* in_sizes, int n_in,
                              void* d_out, int out_size, void* d_ws, size_t ws_size,
                              hipStream_t stream) {
    const float* x    = (const float*)d_in[0];
    const int*   ei   = (const int*)d_in[1];
    const int*   batch= (const int*)d_in[2];
    const float* W1   = (const float*)d_in[4];
    const float* b1   = (const float*)d_in[5];
    const float* W2   = (const float*)d_in[6];
    const float* b2   = (const float*)d_in[7];
    const float* Wc1  = (const float*)d_in[8];
    const float* bc1  = (const float*)d_in[9];
    const float* Wc2  = (const float*)d_in[10];
    const float* bc2  = (const float*)d_in[11];
    float* out = (float*)d_out;

    const int N = in_sizes[0] / 128;
    const int E = in_sizes[1] / 2;
    const int G = out_size / 8;

    const int* src = ei;
    const int* dst = ei + E;

    const int NBK = DIV_UP(N, 256);     // buckets of 256 nodes
    const int NB1 = DIV_UP(E, CH);      // partition blocks

    char* p = (char*)d_ws;
    auto alloc = [&](size_t bytes) {
        char* q = p;
        p += (bytes + 255) & ~(size_t)255;
        return q;
    };
    ushort_t* bufG1    = (ushort_t*)alloc((size_t)(N + 1) * 128 * 2);  // g1 / h2 (bf16) + zero row
    ushort_t* bufG2    = (ushort_t*)alloc((size_t)(N + 1) * 128 * 2);  // g2 (bf16) + zero row
    ushort_t* bufH     = (ushort_t*)alloc((size_t)N * 128 * 2);        // h1 (bf16)
    int*      rowptr   = (int*)     alloc(((size_t)N + 1) * 4);
    int*      colA     = (int*)     alloc((size_t)E * 4 + 256);
    float*    inv_sqrt = (float*)   alloc((size_t)N * 4);
    int*      blk_hist = (int*)     alloc((size_t)NBK * NB1 * 4);
    int*      blk_off  = (int*)     alloc((size_t)NBK * NB1 * 4);
    int*      bkt_base = (int*)     alloc(((size_t)NBK + 1) * 4);
    int*      bktT     = (int*)     alloc((size_t)NBK * 4);
    int*      doneF    = (int*)     alloc(256);
    ushort_t* wT1      = (ushort_t*)alloc(128 * 128 * 2);
    ushort_t* wT2      = (ushort_t*)alloc(128 * 128 * 2);
    float*    pooled   = (float*)   alloc((size_t)G * 128 * 4);
    int*      counts   = (int*)     alloc((size_t)G * 4);

    // part_arr aliases bufG1 (first E*4 bytes; zero row at byte N*256 untouched)
    unsigned int* part_arr = (unsigned int*)bufG1;
    ushort_t* zrow1 = bufG1 + (size_t)N * 128;
    ushort_t* zrow2 = bufG2 + (size_t)N * 128;

    // setup (prepW + zero pooled/counts/zero-rows/done) + CSR build
    k_setup<<<161, 256, 0, stream>>>(W1, W2, wT1, wT2, pooled, counts, G, zrow1, zrow2, doneF);
    k_hist1<<<NB1, 256, 0, stream>>>(dst, E, NBK, NB1, blk_hist);
    k_rowscan<<<NBK, 256, 0, stream>>>(blk_hist, blk_off, bktT, bkt_base, doneF, NBK, NB1, E);
    k_scatter1<<<NB1, 256, 0, stream>>>(src, dst, E, NBK, NB1, blk_off, bkt_base, part_arr);
    k_sortfill<<<NBK, 256, 0, stream>>>(part_arr, bkt_base, N, E, colA, rowptr, inv_sqrt);

    // layer 1: MFMA GEMM (f32 in) -> g1 bf16 ; aggregate -> h1 bf16
    k_gemm_mfma<false><<<DIV_UP(N, 128), 256, 0, stream>>>(x, wT1, inv_sqrt, bufG1, N);
    k_agg<<<DIV_UP(N, 4), 256, 0, stream>>>(bufG1, rowptr, colA, inv_sqrt, b1, bufH, N);

    // layer 2: MFMA GEMM (bf16 in) -> g2 bf16 ; aggregate -> h2 bf16 (reuse bufG1)
    k_gemm_mfma<true><<<DIV_UP(N, 128), 256, 0, stream>>>(bufH, wT2, inv_sqrt, bufG2, N);
    k_agg<<<DIV_UP(N, 4), 256, 0, stream>>>(bufG2, rowptr, colA, inv_sqrt, b2, bufG1, N);

    // pool + head
    k_pool<<<DIV_UP(N, 64), 256, 0, stream>>>(bufG1, batch, pooled, counts, N);
    k_mlp<<<G, 64, 0, stream>>>(pooled, counts, Wc1, bc1, Wc2, bc2, out, G);
}

// Round 16
// 260.755 us; speedup vs baseline: 1.4640x; 1.0607x over previous
//
#include <hip/hip_runtime.h>
#include <hip/hip_bf16.h>

#define DIV_UP(a,b) (((a)+(b)-1)/(b))

#define CH   4608    // edges per partition block (2x parallelism vs 9216)
#define CAP  7424    // max edges per 256-node bucket in sortfill (mean 4096)

typedef unsigned short ushort_t;
typedef unsigned int   uint_t;
typedef __attribute__((ext_vector_type(8))) short bf16x8;   // 8 bf16 = 4 VGPR
typedef __attribute__((ext_vector_type(4))) float f32x4;

__device__ __forceinline__ ushort_t f2bf(float f) {
    __hip_bfloat16 h = __float2bfloat16(f);   // RNE
    ushort_t u;
    __builtin_memcpy(&u, &h, 2);
    return u;
}
__device__ __forceinline__ float bfl(uint_t u) { return __uint_as_float(u << 16); }
__device__ __forceinline__ float bfh(uint_t u) { return __uint_as_float(u & 0xffff0000u); }

// ---------------- Setup + histogram (fused) ----------------
// blocks [0,NB1): per-partition-block dst histogram
// [NB1, NB1+128): W transpose->bf16 ; [NB1+128, NB1+160): zero pooled
// NB1+160: zero counts, zero rows, done flag

__global__ __launch_bounds__(256) void k_setup_hist(const int* __restrict__ dst, int E,
                                               int NBK, int NB1,
                                               int* __restrict__ blk_hist,
                                               const float* __restrict__ W1,
                                               const float* __restrict__ W2,
                                               ushort_t* __restrict__ wT1,
                                               ushort_t* __restrict__ wT2,
                                               float* __restrict__ pooled,
                                               int* __restrict__ counts, int G,
                                               ushort_t* __restrict__ zrow1,
                                               ushort_t* __restrict__ zrow2,
                                               int* __restrict__ done) {
    __shared__ int hist[512];
    int b = blockIdx.x;
    int t = threadIdx.x;
    if (b < NB1) {
        for (int i = t; i < NBK; i += 256) hist[i] = 0;
        __syncthreads();
        int base = b * CH;
        int lim = E - base; if (lim > CH) lim = CH;
        for (int i = t; i < lim; i += 256)
            atomicAdd(&hist[dst[base + i] >> 8], 1);
        __syncthreads();
        for (int k = t; k < NBK; k += 256)
            blk_hist[k * NB1 + b] = hist[k];   // bucket-major
    } else if (b < NB1 + 128) {
        int idx = (b - NB1) * 256 + t;
        const float* W = (idx < 16384) ? W1 : W2;
        ushort_t*    O = (idx < 16384) ? wT1 : wT2;
        int j = idx & 16383;
        int k = j >> 7, c = j & 127;
        O[c * 128 + k] = f2bf(W[j]);
    } else if (b < NB1 + 160) {
        int i = (b - NB1 - 128) * 256 + t;
        if (i < G * 128) pooled[i] = 0.f;
    } else {
        if (t < 128) { zrow1[t] = 0; zrow2[t] = 0; }
        for (int i = t; i < G; i += 256) counts[i] = 0;
        if (t == 0) *done = 0;
    }
}

// ---- row scan + (last block) bucket-total scan, fused via done-counter ----

__global__ __launch_bounds__(256) void k_rowscan(const int* __restrict__ blk_hist,
                                                 int* __restrict__ blk_off,
                                                 int* __restrict__ T,
                                                 int* __restrict__ bkt_base,
                                                 int* __restrict__ done,
                                                 int NBK, int NB1, int E) {
    __shared__ int s[256];
    __shared__ int amLast;
    int b = blockIdx.x;
    const int* row = blk_hist + (size_t)b * NB1;
    int* orow = blk_off + (size_t)b * NB1;
    int t = threadIdx.x;
    int K = DIV_UP(NB1, 256);
    int lo = t * K;
    int hi = lo + K; if (hi > NB1) hi = NB1;
    int sum = 0;
    for (int i = lo; i < hi; i++) sum += row[i];
    s[t] = sum;
    __syncthreads();
    for (int o = 1; o < 256; o <<= 1) {
        int v = (t >= o) ? s[t - o] : 0;
        __syncthreads();
        s[t] += v;
        __syncthreads();
    }
    int run = s[t] - sum;   // exclusive prefix of this thread's chunk
    for (int i = lo; i < hi; i++) { orow[i] = run; run += row[i]; }
    if (t == 255) atomicExch(&T[b], s[255]);    // device-coherent publish
    __syncthreads();
    if (t == 0) amLast = (atomicAdd(done, 1) == NBK - 1);
    __syncthreads();
    if (!amLast) return;

    // last block: scan bucket totals -> bkt_base (atomic reads for coherence)
    int K2 = DIV_UP(NBK, 256);
    int lo2 = t * K2;
    int hi2 = lo2 + K2; if (hi2 > NBK) hi2 = NBK;
    int tv[8];
    int sum2 = 0;
    for (int i = lo2, j = 0; i < hi2; i++, j++) { tv[j] = atomicAdd(&T[i], 0); sum2 += tv[j]; }
    s[t] = sum2;
    __syncthreads();
    for (int o = 1; o < 256; o <<= 1) {
        int v = (t >= o) ? s[t - o] : 0;
        __syncthreads();
        s[t] += v;
        __syncthreads();
    }
    int run2 = s[t] - sum2;
    for (int i = lo2, j = 0; i < hi2; i++, j++) { bkt_base[i] = run2; run2 += tv[j]; }
    if (t == 0) bkt_base[NBK] = E;
}

// ---- scatter: group edges by bucket in LDS, copy out coalesced ----

__global__ __launch_bounds__(256) void k_scatter1(const int* __restrict__ src,
                                                  const int* __restrict__ dst, int E,
                                                  int NBK, int NB1,
                                                  const int* __restrict__ blk_off,
                                                  const int* __restrict__ bkt_base,
                                                  unsigned int* __restrict__ part_arr) {
    __shared__ unsigned int   stage[CH];
    __shared__ unsigned short bko[CH];
    __shared__ int hist[512];
    __shared__ int cur[512];
    __shared__ int off[512];

    int t = threadIdx.x;
    hist[t] = 0; hist[t + 256] = 0;
    __syncthreads();

    int base = blockIdx.x * CH;
    int lim = E - base; if (lim > CH) lim = CH;

    for (int i = t; i < lim; i += 256)
        atomicAdd(&hist[dst[base + i] >> 8], 1);
    __syncthreads();

    int c0 = hist[t], c1 = hist[t + 256];
    for (int o = 1; o < 512; o <<= 1) {
        int v0 = (t >= o) ? hist[t - o] : 0;
        int v1 = hist[t + 256 - o];
        __syncthreads();
        hist[t] += v0;
        hist[t + 256] += v1;
        __syncthreads();
    }
    int e0 = hist[t] - c0;          // exclusive
    int e1 = hist[t + 256] - c1;
    cur[t] = e0; cur[t + 256] = e1;
    if (t < NBK)       off[t]       = blk_off[t * NB1 + blockIdx.x] + bkt_base[t] - e0;
    if (t + 256 < NBK) off[t + 256] = blk_off[(t + 256) * NB1 + blockIdx.x] + bkt_base[t + 256] - e1;
    __syncthreads();

    for (int i = t; i < lim; i += 256) {
        int d = dst[base + i];
        int sv = src[base + i];
        int b = d >> 8;
        int slot = atomicAdd(&cur[b], 1);
        stage[slot] = ((unsigned int)sv << 8) | (unsigned int)(d & 255);
        bko[slot] = (unsigned short)b;
    }
    __syncthreads();

    for (int i = t; i < lim; i += 256) {
        int b = bko[i];
        part_arr[off[b] + i] = stage[i];
    }
}

// ---- sortfill: per-bucket LDS counting sort, 512 threads ----

__global__ __launch_bounds__(512) void k_sortfill(const unsigned int* __restrict__ part_arr,
                                                  const int* __restrict__ bkt_base,
                                                  int N, int E,
                                                  int* __restrict__ col,
                                                  int* __restrict__ rowptr,
                                                  float* __restrict__ inv_sqrt) {
    __shared__ unsigned int in_[CAP];
    __shared__ int outS[CAP];
    __shared__ int hist[256];
    __shared__ int scn[256];
    __shared__ int cur[256];

    int b = blockIdx.x;
    int base = bkt_base[b];
    int nb   = bkt_base[b + 1] - base;
    int t = threadIdx.x;    // 0..511

    if (t < 256) hist[t] = 0;
    __syncthreads();

    for (int i = t; i < nb; i += 512) {
        unsigned int pk = part_arr[base + i];
        in_[i] = pk;
        atomicAdd(&hist[pk & 255u], 1);
    }
    __syncthreads();

    int cnt = (t < 256) ? hist[t] : 0;
    for (int o = 1; o < 256; o <<= 1) {
        int v = (t >= o && t < 256) ? hist[t - o] : 0;
        __syncthreads();
        if (t < 256) hist[t] += v;
        __syncthreads();
    }
    if (t < 256) {
        scn[t] = hist[t] - cnt;     // exclusive
        cur[t] = 0;
    }
    __syncthreads();

    for (int i = t; i < nb; i += 512) {
        unsigned int pk = in_[i];
        int d = (int)(pk & 255u);
        int r = atomicAdd(&cur[d], 1);
        outS[scn[d] + r] = (int)(pk >> 8);
    }
    __syncthreads();

    for (int i = t; i < nb; i += 512) col[base + i] = outS[i];

    if (t < 256) {
        int node = b * 256 + t;
        if (node < N) {
            rowptr[node] = base + scn[t];
            inv_sqrt[node] = rsqrtf((float)(cnt + 1));   // +1: self-loop
        }
    }
    if (b == 0 && t == 0) rowptr[N] = E;
}

// ---------------- MFMA GEMM: outg[n][c] = bf16(inv_sqrt[n] * (X @ W)[n][c]) ----------------

template <bool BF16IN>
__global__ __launch_bounds__(256) void k_gemm_mfma(const void* __restrict__ inp,
                        const ushort_t* __restrict__ wT,   // [128 c][128 k] bf16
                        const float* __restrict__ inv_sqrt,
                        ushort_t* __restrict__ outg, int N) {
    __shared__ ushort_t xs[128][56];   // [node][k]
    __shared__ ushort_t ws[128][56];   // [col][k]
    __shared__ float ivs[128];

    const int t = threadIdx.x;
    const int row0 = blockIdx.x * 128;
    const int lane = t & 63;
    const int wv = t >> 6;
    const int wrN = wv >> 1;        // node quadrant *64
    const int wcC = wv & 1;         // col quadrant *64
    const int lh = lane >> 4;       // 0..3
    const int ll = lane & 15;

    const bool full = (row0 + 128 <= N);

    if (t < 128) {
        int r = row0 + t;
        ivs[t] = inv_sqrt[(full || r < N) ? r : 0];
    }

    f32x4 acc[4][4];   // [cb][nb]
    #pragma unroll
    for (int a = 0; a < 4; a++)
        #pragma unroll
        for (int b = 0; b < 4; b++)
            acc[a][b] = (f32x4){0.f, 0.f, 0.f, 0.f};

    const uint4* wT16 = (const uint4*)wT;   // row = 16 uint4

    for (int kt = 0; kt < 4; kt++) {
        if (BF16IN) {
            const uint4* in16 = (const uint4*)inp;
            #pragma unroll
            for (int i = 0; i < 2; i++) {
                int fq = t + i * 256;       // 0..511
                int r = fq >> 2, q = fq & 3;
                int row = row0 + r;
                uint4 v = make_uint4(0u, 0u, 0u, 0u);
                if (full || row < N) v = in16[(size_t)row * 16 + kt * 4 + q];
                *(uint4*)&xs[r][q * 8] = v;
            }
        } else {
            const float4* in4 = (const float4*)inp;
            #pragma unroll
            for (int i = 0; i < 4; i++) {
                int fq = t + i * 256;       // 0..1023
                int r = fq >> 3, q = fq & 7;
                int row = row0 + r;
                float4 v = make_float4(0.f, 0.f, 0.f, 0.f);
                if (full || row < N) v = in4[(size_t)row * 32 + kt * 8 + q];
                uint2 u;
                u.x = (uint_t)f2bf(v.x) | ((uint_t)f2bf(v.y) << 16);
                u.y = (uint_t)f2bf(v.z) | ((uint_t)f2bf(v.w) << 16);
                *(uint2*)&xs[r][q * 4] = u;
            }
        }
        #pragma unroll
        for (int i = 0; i < 2; i++) {
            int cq = t + i * 256;           // 0..511
            int c = cq >> 2, q = cq & 3;
            *(uint4*)&ws[c][q * 8] = wT16[(size_t)c * 16 + kt * 4 + q];
        }
        __syncthreads();

        bf16x8 aF[4], bF[4];
        #pragma unroll
        for (int nb = 0; nb < 4; nb++)
            aF[nb] = *(const bf16x8*)&xs[wrN * 64 + nb * 16 + ll][lh * 8];
        #pragma unroll
        for (int cb = 0; cb < 4; cb++)
            bF[cb] = *(const bf16x8*)&ws[wcC * 64 + cb * 16 + ll][lh * 8];
        #pragma unroll
        for (int cb = 0; cb < 4; cb++)
            #pragma unroll
            for (int nb = 0; nb < 4; nb++)
                acc[cb][nb] = __builtin_amdgcn_mfma_f32_16x16x32_bf16(
                                  bF[cb], aF[nb], acc[cb][nb], 0, 0, 0);
        __syncthreads();
    }

    #pragma unroll
    for (int nb = 0; nb < 4; nb++) {
        int lr = wrN * 64 + nb * 16 + ll;
        int row = row0 + lr;
        if (full || row < N) {
            float s = ivs[lr];
            #pragma unroll
            for (int cb = 0; cb < 4; cb++) {
                f32x4 a = acc[cb][nb];
                uint2 u;
                u.x = (uint_t)f2bf(s * a.x) | ((uint_t)f2bf(s * a.y) << 16);
                u.y = (uint_t)f2bf(s * a.z) | ((uint_t)f2bf(s * a.w) << 16);
                int colb = wcC * 64 + cb * 16 + lh * 4;
                *(uint2*)(outg + (size_t)row * 128 + colb) = u;
            }
        }
    }
}

// ---------------- Aggregate: zero-row dummies, unconditional accumulate ----------------

__global__ __launch_bounds__(256) void k_agg(const ushort_t* __restrict__ g,
                            const int* __restrict__ rowptr,
                            const int* __restrict__ col, const float* __restrict__ inv_sqrt,
                            const float* __restrict__ bias, ushort_t* __restrict__ outh, int N) {
    int wid  = (blockIdx.x * blockDim.x + threadIdx.x) >> 6;   // node
    int lane = threadIdx.x & 63;
    if (wid >= N) return;

    int start = rowptr[wid];
    int end   = rowptr[wid + 1];

    const uint_t* g1 = (const uint_t*)g;    // row = 64 uints (128 bf16)
    float accx = 0.f, accy = 0.f;

    for (int tt = start; tt < end; tt += 16) {
        int idx[16];
        #pragma unroll
        for (int i = 0; i < 16; i++)
            idx[i] = (tt + i < end) ? col[tt + i] : N;   // N = zero row
        uint_t v[16];
        #pragma unroll
        for (int i = 0; i < 16; i++)
            v[i] = g1[(size_t)((unsigned)idx[i] * 64u + (unsigned)lane)];
        #pragma unroll
        for (int i = 0; i < 16; i++) {
            accx += bfl(v[i]);
            accy += bfh(v[i]);
        }
    }

    uint_t sv = g1[(unsigned)wid * 64u + (unsigned)lane];
    accx += bfl(sv);
    accy += bfh(sv);

    float is = inv_sqrt[wid];
    float2 b = ((const float2*)bias)[lane];
    float ox = fmaxf(fmaf(is, accx, b.x), 0.f);
    float oy = fmaxf(fmaf(is, accy, b.y), 0.f);
    uint_t pk = (uint_t)f2bf(ox) | ((uint_t)f2bf(oy) << 16);
    ((uint_t*)outh)[(size_t)wid * 64 + lane] = pk;
}

// ---------------- Pool: parallel, wave = 16 rows, lane = feature pair ----------------

__global__ __launch_bounds__(256) void k_pool(const ushort_t* __restrict__ h,
                       const int* __restrict__ batch,
                       float* __restrict__ pooled, int* __restrict__ counts, int N) {
    int w    = threadIdx.x >> 6;          // wave 0..3
    int lane = threadIdx.x & 63;
    int row0 = blockIdx.x * 64 + w * 16;
    if (row0 >= N) return;
    int nr = N - row0; if (nr > 16) nr = 16;

    const uint_t* h1 = (const uint_t*)h;

    uint_t v[16];
    int    bb[16];
    #pragma unroll
    for (int i = 0; i < 16; i++) {
        int r = (i < nr) ? row0 + i : row0;
        v[i]  = h1[(size_t)r * 64 + lane];
        bb[i] = batch[r];
    }

    float ax = 0.f, ay = 0.f;
    int cnt = 0;
    int cur = bb[0];
    #pragma unroll
    for (int i = 0; i < 16; i++) {
        if (i < nr) {
            if (bb[i] != cur) {
                atomicAdd(&pooled[(size_t)cur * 128 + lane * 2],     ax);
                atomicAdd(&pooled[(size_t)cur * 128 + lane * 2 + 1], ay);
                if (lane == 0) atomicAdd(&counts[cur], cnt);
                ax = 0.f; ay = 0.f; cnt = 0; cur = bb[i];
            }
            ax += bfl(v[i]);
            ay += bfh(v[i]);
            cnt++;
        }
    }
    atomicAdd(&pooled[(size_t)cur * 128 + lane * 2],     ax);
    atomicAdd(&pooled[(size_t)cur * 128 + lane * 2 + 1], ay);
    if (lane == 0) atomicAdd(&counts[cur], cnt);
}

// ---------------- MLP head ----------------

__global__ void k_mlp(const float* __restrict__ pooled, const int* __restrict__ counts,
                      const float* __restrict__ Wc1, const float* __restrict__ bc1,
                      const float* __restrict__ Wc2, const float* __restrict__ bc2,
                      float* __restrict__ out, int G) {
    int g = blockIdx.x;
    int j = threadIdx.x;    // 0..63
    __shared__ float pm[128];
    __shared__ float z[64];

    float invc = 1.0f / fmaxf((float)counts[g], 1.0f);
    pm[j]      = pooled[(size_t)g * 128 + j] * invc;
    pm[j + 64] = pooled[(size_t)g * 128 + 64 + j] * invc;
    __syncthreads();

    float a = bc1[j];
    #pragma unroll 8
    for (int k = 0; k < 128; k++) a += pm[k] * Wc1[k * 64 + j];
    z[j] = fmaxf(a, 0.f);
    __syncthreads();

    if (j < 8) {
        float o = bc2[j];
        #pragma unroll 8
        for (int k = 0; k < 64; k++) o += z[k] * Wc2[k * 8 + j];
        out[(size_t)g * 8 + j] = o;
    }
}

// ---------------- launch ----------------

extern "C" void kernel_launch(void* const* d_in, const int* in_sizes, int n_in,
                              void* d_out, int out_size, void* d_ws, size_t ws_size,
                              hipStream_t stream) {
    const float* x    = (const float*)d_in[0];
    const int*   ei   = (const int*)d_in[1];
    const int*   batch= (const int*)d_in[2];
    const float* W1   = (const float*)d_in[4];
    const float* b1   = (const float*)d_in[5];
    const float* W2   = (const float*)d_in[6];
    const float* b2   = (const float*)d_in[7];
    const float* Wc1  = (const float*)d_in[8];
    const float* bc1  = (const float*)d_in[9];
    const float* Wc2  = (const float*)d_in[10];
    const float* bc2  = (const float*)d_in[11];
    float* out = (float*)d_out;

    const int N = in_sizes[0] / 128;
    const int E = in_sizes[1] / 2;
    const int G = out_size / 8;

    const int* src = ei;
    const int* dst = ei + E;

    const int NBK = DIV_UP(N, 256);     // buckets of 256 nodes
    const int NB1 = DIV_UP(E, CH);      // partition blocks

    char* p = (char*)d_ws;
    auto alloc = [&](size_t bytes) {
        char* q = p;
        p += (bytes + 255) & ~(size_t)255;
        return q;
    };
    ushort_t* bufG1    = (ushort_t*)alloc((size_t)(N + 1) * 128 * 2);  // g1 / h2 (bf16) + zero row
    ushort_t* bufG2    = (ushort_t*)alloc((size_t)(N + 1) * 128 * 2);  // g2 (bf16) + zero row
    ushort_t* bufH     = (ushort_t*)alloc((size_t)N * 128 * 2);        // h1 (bf16)
    int*      rowptr   = (int*)     alloc(((size_t)N + 1) * 4);
    int*      colA     = (int*)     alloc((size_t)E * 4 + 256);
    float*    inv_sqrt = (float*)   alloc((size_t)N * 4);
    int*      blk_hist = (int*)     alloc((size_t)NBK * NB1 * 4);
    int*      blk_off  = (int*)     alloc((size_t)NBK * NB1 * 4);
    int*      bkt_base = (int*)     alloc(((size_t)NBK + 1) * 4);
    int*      bktT     = (int*)     alloc((size_t)NBK * 4);
    int*      doneF    = (int*)     alloc(256);
    ushort_t* wT1      = (ushort_t*)alloc(128 * 128 * 2);
    ushort_t* wT2      = (ushort_t*)alloc(128 * 128 * 2);
    float*    pooled   = (float*)   alloc((size_t)G * 128 * 4);
    int*      counts   = (int*)     alloc((size_t)G * 4);

    // part_arr aliases bufG1 (first E*4 bytes; zero row at offset N*128 is beyond E*4? no —
    // E*4 = 6.4MB < N*256B = 25.6MB, so zero row region is untouched by part_arr writes
    // only if N*128 uints > E... it isn't; but k_sortfill consumes part_arr BEFORE
    // GEMM1 writes bufG1, and zero rows are re-used only by k_agg afterwards. The
    // zero row lives at bufG1 + N*128 (beyond part_arr's E entries = 1.6M uints =
    // offset 1.6M < N*64 = 6.4M uints). Safe: setup zeroes it, part_arr never reaches it.
    unsigned int* part_arr = (unsigned int*)bufG1;
    ushort_t* zrow1 = bufG1 + (size_t)N * 128;
    ushort_t* zrow2 = bufG2 + (size_t)N * 128;

    // setup + histogram (fused) ; CSR build
    k_setup_hist<<<NB1 + 161, 256, 0, stream>>>(dst, E, NBK, NB1, blk_hist,
                                                W1, W2, wT1, wT2, pooled, counts, G,
                                                zrow1, zrow2, doneF);
    k_rowscan<<<NBK, 256, 0, stream>>>(blk_hist, blk_off, bktT, bkt_base, doneF, NBK, NB1, E);
    k_scatter1<<<NB1, 256, 0, stream>>>(src, dst, E, NBK, NB1, blk_off, bkt_base, part_arr);
    k_sortfill<<<NBK, 512, 0, stream>>>(part_arr, bkt_base, N, E, colA, rowptr, inv_sqrt);

    // layer 1: MFMA GEMM (f32 in) -> g1 bf16 ; aggregate -> h1 bf16
    k_gemm_mfma<false><<<DIV_UP(N, 128), 256, 0, stream>>>(x, wT1, inv_sqrt, bufG1, N);
    k_agg<<<DIV_UP(N, 4), 256, 0, stream>>>(bufG1, rowptr, colA, inv_sqrt, b1, bufH, N);

    // layer 2: MFMA GEMM (bf16 in) -> g2 bf16 ; aggregate -> h2 bf16 (reuse bufG1)
    k_gemm_mfma<true><<<DIV_UP(N, 128), 256, 0, stream>>>(bufH, wT2, inv_sqrt, bufG2, N);
    k_agg<<<DIV_UP(N, 4), 256, 0, stream>>>(bufG2, rowptr, colA, inv_sqrt, b2, bufG1, N);

    // pool + head
    k_pool<<<DIV_UP(N, 64), 256, 0, stream>>>(bufG1, batch, pooled, counts, N);
    k_mlp<<<G, 64, 0, stream>>>(pooled, counts, Wc1, bc1, Wc2, bc2, out, G);
}

// Round 17
// 254.374 us; speedup vs baseline: 1.5007x; 1.0251x over previous
//
#include <hip/hip_runtime.h>
#include <hip/hip_bf16.h>

#define DIV_UP(a,b) (((a)+(b)-1)/(b))

#define CH   4608    // edges per partition block
#define CAP  7424    // max edges per 256-node bucket in sortfill (mean 4096)

typedef unsigned short ushort_t;
typedef unsigned int   uint_t;
typedef __attribute__((ext_vector_type(8))) short bf16x8;   // 8 bf16 = 4 VGPR
typedef __attribute__((ext_vector_type(4))) float f32x4;

__device__ __forceinline__ ushort_t f2bf(float f) {
    __hip_bfloat16 h = __float2bfloat16(f);   // RNE
    ushort_t u;
    __builtin_memcpy(&u, &h, 2);
    return u;
}
__device__ __forceinline__ float bfl(uint_t u) { return __uint_as_float(u << 16); }
__device__ __forceinline__ float bfh(uint_t u) { return __uint_as_float(u & 0xffff0000u); }

// ---------------- Setup + histogram (fused) ----------------

__global__ __launch_bounds__(256) void k_setup_hist(const int* __restrict__ dst, int E,
                                               int NBK, int NB1,
                                               int* __restrict__ blk_hist,
                                               const float* __restrict__ W1,
                                               const float* __restrict__ W2,
                                               ushort_t* __restrict__ wT1,
                                               ushort_t* __restrict__ wT2,
                                               float* __restrict__ pooled,
                                               int* __restrict__ counts, int G,
                                               ushort_t* __restrict__ zrow1,
                                               ushort_t* __restrict__ zrow2,
                                               int* __restrict__ done) {
    __shared__ int hist[512];
    int b = blockIdx.x;
    int t = threadIdx.x;
    if (b < NB1) {
        for (int i = t; i < NBK; i += 256) hist[i] = 0;
        __syncthreads();
        int base = b * CH;
        int lim = E - base; if (lim > CH) lim = CH;
        for (int i = t; i < lim; i += 256)
            atomicAdd(&hist[dst[base + i] >> 8], 1);
        __syncthreads();
        for (int k = t; k < NBK; k += 256)
            blk_hist[k * NB1 + b] = hist[k];   // bucket-major
    } else if (b < NB1 + 128) {
        int idx = (b - NB1) * 256 + t;
        const float* W = (idx < 16384) ? W1 : W2;
        ushort_t*    O = (idx < 16384) ? wT1 : wT2;
        int j = idx & 16383;
        int k = j >> 7, c = j & 127;
        O[c * 128 + k] = f2bf(W[j]);
    } else if (b < NB1 + 160) {
        int i = (b - NB1 - 128) * 256 + t;
        if (i < G * 128) pooled[i] = 0.f;
    } else {
        if (t < 128) { zrow1[t] = 0; zrow2[t] = 0; }
        for (int i = t; i < G; i += 256) counts[i] = 0;
        if (t == 0) *done = 0;
    }
}

// ---- row scan + (last block) bucket-total scan, fused via done-counter ----

__global__ __launch_bounds__(256) void k_rowscan(const int* __restrict__ blk_hist,
                                                 int* __restrict__ blk_off,
                                                 int* __restrict__ T,
                                                 int* __restrict__ bkt_base,
                                                 int* __restrict__ done,
                                                 int NBK, int NB1, int E) {
    __shared__ int s[256];
    __shared__ int amLast;
    int b = blockIdx.x;
    const int* row = blk_hist + (size_t)b * NB1;
    int* orow = blk_off + (size_t)b * NB1;
    int t = threadIdx.x;
    int K = DIV_UP(NB1, 256);
    int lo = t * K;
    int hi = lo + K; if (hi > NB1) hi = NB1;
    int sum = 0;
    for (int i = lo; i < hi; i++) sum += row[i];
    s[t] = sum;
    __syncthreads();
    for (int o = 1; o < 256; o <<= 1) {
        int v = (t >= o) ? s[t - o] : 0;
        __syncthreads();
        s[t] += v;
        __syncthreads();
    }
    int run = s[t] - sum;   // exclusive prefix of this thread's chunk
    for (int i = lo; i < hi; i++) { orow[i] = run; run += row[i]; }
    if (t == 255) atomicExch(&T[b], s[255]);    // device-coherent publish
    __syncthreads();
    if (t == 0) amLast = (atomicAdd(done, 1) == NBK - 1);
    __syncthreads();
    if (!amLast) return;

    int K2 = DIV_UP(NBK, 256);
    int lo2 = t * K2;
    int hi2 = lo2 + K2; if (hi2 > NBK) hi2 = NBK;
    int tv[8];
    int sum2 = 0;
    for (int i = lo2, j = 0; i < hi2; i++, j++) { tv[j] = atomicAdd(&T[i], 0); sum2 += tv[j]; }
    s[t] = sum2;
    __syncthreads();
    for (int o = 1; o < 256; o <<= 1) {
        int v = (t >= o) ? s[t - o] : 0;
        __syncthreads();
        s[t] += v;
        __syncthreads();
    }
    int run2 = s[t] - sum2;
    for (int i = lo2, j = 0; i < hi2; i++, j++) { bkt_base[i] = run2; run2 += tv[j]; }
    if (t == 0) bkt_base[NBK] = E;
}

// ---- scatter: group edges by bucket in LDS, copy out coalesced ----

__global__ __launch_bounds__(256) void k_scatter1(const int* __restrict__ src,
                                                  const int* __restrict__ dst, int E,
                                                  int NBK, int NB1,
                                                  const int* __restrict__ blk_off,
                                                  const int* __restrict__ bkt_base,
                                                  unsigned int* __restrict__ part_arr) {
    __shared__ unsigned int   stage[CH];
    __shared__ unsigned short bko[CH];
    __shared__ int hist[512];
    __shared__ int cur[512];
    __shared__ int off[512];

    int t = threadIdx.x;
    hist[t] = 0; hist[t + 256] = 0;
    __syncthreads();

    int base = blockIdx.x * CH;
    int lim = E - base; if (lim > CH) lim = CH;

    for (int i = t; i < lim; i += 256)
        atomicAdd(&hist[dst[base + i] >> 8], 1);
    __syncthreads();

    int c0 = hist[t], c1 = hist[t + 256];
    for (int o = 1; o < 512; o <<= 1) {
        int v0 = (t >= o) ? hist[t - o] : 0;
        int v1 = hist[t + 256 - o];
        __syncthreads();
        hist[t] += v0;
        hist[t + 256] += v1;
        __syncthreads();
    }
    int e0 = hist[t] - c0;          // exclusive
    int e1 = hist[t + 256] - c1;
    cur[t] = e0; cur[t + 256] = e1;
    if (t < NBK)       off[t]       = blk_off[t * NB1 + blockIdx.x] + bkt_base[t] - e0;
    if (t + 256 < NBK) off[t + 256] = blk_off[(t + 256) * NB1 + blockIdx.x] + bkt_base[t + 256] - e1;
    __syncthreads();

    for (int i = t; i < lim; i += 256) {
        int d = dst[base + i];
        int sv = src[base + i];
        int b = d >> 8;
        int slot = atomicAdd(&cur[b], 1);
        stage[slot] = ((unsigned int)sv << 8) | (unsigned int)(d & 255);
        bko[slot] = (unsigned short)b;
    }
    __syncthreads();

    for (int i = t; i < lim; i += 256) {
        int b = bko[i];
        part_arr[off[b] + i] = stage[i];
    }
}

// ---- sortfill: per-bucket LDS counting sort, 512 threads ----

__global__ __launch_bounds__(512) void k_sortfill(const unsigned int* __restrict__ part_arr,
                                                  const int* __restrict__ bkt_base,
                                                  int N, int E,
                                                  int* __restrict__ col,
                                                  int* __restrict__ rowptr,
                                                  float* __restrict__ inv_sqrt) {
    __shared__ unsigned int in_[CAP];
    __shared__ int outS[CAP];
    __shared__ int hist[256];
    __shared__ int scn[256];
    __shared__ int cur[256];

    int b = blockIdx.x;
    int base = bkt_base[b];
    int nb   = bkt_base[b + 1] - base;
    int t = threadIdx.x;    // 0..511

    if (t < 256) hist[t] = 0;
    __syncthreads();

    for (int i = t; i < nb; i += 512) {
        unsigned int pk = part_arr[base + i];
        in_[i] = pk;
        atomicAdd(&hist[pk & 255u], 1);
    }
    __syncthreads();

    int cnt = (t < 256) ? hist[t] : 0;
    for (int o = 1; o < 256; o <<= 1) {
        int v = (t >= o && t < 256) ? hist[t - o] : 0;
        __syncthreads();
        if (t < 256) hist[t] += v;
        __syncthreads();
    }
    if (t < 256) {
        scn[t] = hist[t] - cnt;     // exclusive
        cur[t] = 0;
    }
    __syncthreads();

    for (int i = t; i < nb; i += 512) {
        unsigned int pk = in_[i];
        int d = (int)(pk & 255u);
        int r = atomicAdd(&cur[d], 1);
        outS[scn[d] + r] = (int)(pk >> 8);
    }
    __syncthreads();

    for (int i = t; i < nb; i += 512) col[base + i] = outS[i];

    if (t < 256) {
        int node = b * 256 + t;
        if (node < N) {
            rowptr[node] = base + scn[t];
            inv_sqrt[node] = rsqrtf((float)(cnt + 1));   // +1: self-loop
        }
    }
    if (b == 0 && t == 0) rowptr[N] = E;
}

// ---------------- MFMA GEMM: outg[n][c] = bf16(inv_sqrt[n] * (X @ W)[n][c]) ----------------

template <bool BF16IN>
__global__ __launch_bounds__(256) void k_gemm_mfma(const void* __restrict__ inp,
                        const ushort_t* __restrict__ wT,   // [128 c][128 k] bf16
                        const float* __restrict__ inv_sqrt,
                        ushort_t* __restrict__ outg, int N) {
    __shared__ ushort_t xs[128][56];   // [node][k]
    __shared__ ushort_t ws[128][56];   // [col][k]
    __shared__ float ivs[128];

    const int t = threadIdx.x;
    const int row0 = blockIdx.x * 128;
    const int lane = t & 63;
    const int wv = t >> 6;
    const int wrN = wv >> 1;        // node quadrant *64
    const int wcC = wv & 1;         // col quadrant *64
    const int lh = lane >> 4;       // 0..3
    const int ll = lane & 15;

    const bool full = (row0 + 128 <= N);

    if (t < 128) {
        int r = row0 + t;
        ivs[t] = inv_sqrt[(full || r < N) ? r : 0];
    }

    f32x4 acc[4][4];   // [cb][nb]
    #pragma unroll
    for (int a = 0; a < 4; a++)
        #pragma unroll
        for (int b = 0; b < 4; b++)
            acc[a][b] = (f32x4){0.f, 0.f, 0.f, 0.f};

    const uint4* wT16 = (const uint4*)wT;   // row = 16 uint4

    for (int kt = 0; kt < 4; kt++) {
        if (BF16IN) {
            const uint4* in16 = (const uint4*)inp;
            #pragma unroll
            for (int i = 0; i < 2; i++) {
                int fq = t + i * 256;       // 0..511
                int r = fq >> 2, q = fq & 3;
                int row = row0 + r;
                uint4 v = make_uint4(0u, 0u, 0u, 0u);
                if (full || row < N) v = in16[(size_t)row * 16 + kt * 4 + q];
                *(uint4*)&xs[r][q * 8] = v;
            }
        } else {
            const float4* in4 = (const float4*)inp;
            #pragma unroll
            for (int i = 0; i < 4; i++) {
                int fq = t + i * 256;       // 0..1023
                int r = fq >> 3, q = fq & 7;
                int row = row0 + r;
                float4 v = make_float4(0.f, 0.f, 0.f, 0.f);
                if (full || row < N) v = in4[(size_t)row * 32 + kt * 8 + q];
                uint2 u;
                u.x = (uint_t)f2bf(v.x) | ((uint_t)f2bf(v.y) << 16);
                u.y = (uint_t)f2bf(v.z) | ((uint_t)f2bf(v.w) << 16);
                *(uint2*)&xs[r][q * 4] = u;
            }
        }
        #pragma unroll
        for (int i = 0; i < 2; i++) {
            int cq = t + i * 256;           // 0..511
            int c = cq >> 2, q = cq & 3;
            *(uint4*)&ws[c][q * 8] = wT16[(size_t)c * 16 + kt * 4 + q];
        }
        __syncthreads();

        bf16x8 aF[4], bF[4];
        #pragma unroll
        for (int nb = 0; nb < 4; nb++)
            aF[nb] = *(const bf16x8*)&xs[wrN * 64 + nb * 16 + ll][lh * 8];
        #pragma unroll
        for (int cb = 0; cb < 4; cb++)
            bF[cb] = *(const bf16x8*)&ws[wcC * 64 + cb * 16 + ll][lh * 8];
        #pragma unroll
        for (int cb = 0; cb < 4; cb++)
            #pragma unroll
            for (int nb = 0; nb < 4; nb++)
                acc[cb][nb] = __builtin_amdgcn_mfma_f32_16x16x32_bf16(
                                  bF[cb], aF[nb], acc[cb][nb], 0, 0, 0);
        __syncthreads();
    }

    #pragma unroll
    for (int nb = 0; nb < 4; nb++) {
        int lr = wrN * 64 + nb * 16 + ll;
        int row = row0 + lr;
        if (full || row < N) {
            float s = ivs[lr];
            #pragma unroll
            for (int cb = 0; cb < 4; cb++) {
                f32x4 a = acc[cb][nb];
                uint2 u;
                u.x = (uint_t)f2bf(s * a.x) | ((uint_t)f2bf(s * a.y) << 16);
                u.y = (uint_t)f2bf(s * a.z) | ((uint_t)f2bf(s * a.w) << 16);
                int colb = wcC * 64 + cb * 16 + lh * 4;
                *(uint2*)(outg + (size_t)row * 128 + colb) = u;
            }
        }
    }
}

// ---------------- Aggregate: scalarized wave-uniform index path ----------------
// h[n] = relu(inv_sqrt[n]*(sum g[col] + g[n]) + b), packed bf16 out.
// wid forced through readfirstlane -> rowptr/col loads become s_load;
// 16 gathers in flight; dummy idx -> row N (all zeros), unconditional accum.

__global__ __launch_bounds__(256) void k_agg(const ushort_t* __restrict__ g,
                            const int* __restrict__ rowptr,
                            const int* __restrict__ col, const float* __restrict__ inv_sqrt,
                            const float* __restrict__ bias, ushort_t* __restrict__ outh, int N) {
    int wid0 = (blockIdx.x * blockDim.x + threadIdx.x) >> 6;   // wave-uniform node id
    int wid  = __builtin_amdgcn_readfirstlane(wid0);           // force SGPR
    int lane = threadIdx.x & 63;
    if (wid >= N) return;

    int start = __builtin_amdgcn_readfirstlane(rowptr[wid]);
    int end   = __builtin_amdgcn_readfirstlane(rowptr[wid + 1]);

    const uint_t* g1 = (const uint_t*)g;    // row = 64 uints (128 bf16)
    float accx = 0.f, accy = 0.f;

    for (int tt = start; tt < end; tt += 16) {
        int idx[16];
        #pragma unroll
        for (int i = 0; i < 16; i++)
            idx[i] = (tt + i < end) ? col[tt + i] : N;   // N = zero row
        uint_t v[16];
        #pragma unroll
        for (int i = 0; i < 16; i++)
            v[i] = g1[(size_t)((unsigned)idx[i] * 64u + (unsigned)lane)];
        #pragma unroll
        for (int i = 0; i < 16; i++) {
            accx += bfl(v[i]);
            accy += bfh(v[i]);
        }
    }

    uint_t sv = g1[(unsigned)wid * 64u + (unsigned)lane];
    accx += bfl(sv);
    accy += bfh(sv);

    float is = inv_sqrt[wid];
    float2 b = ((const float2*)bias)[lane];
    float ox = fmaxf(fmaf(is, accx, b.x), 0.f);
    float oy = fmaxf(fmaf(is, accy, b.y), 0.f);
    uint_t pk = (uint_t)f2bf(ox) | ((uint_t)f2bf(oy) << 16);
    ((uint_t*)outh)[(size_t)wid * 64 + lane] = pk;
}

// ---------------- Pool: parallel, wave = 16 rows, lane = feature pair ----------------

__global__ __launch_bounds__(256) void k_pool(const ushort_t* __restrict__ h,
                       const int* __restrict__ batch,
                       float* __restrict__ pooled, int* __restrict__ counts, int N) {
    int w    = threadIdx.x >> 6;          // wave 0..3
    int lane = threadIdx.x & 63;
    int row0 = blockIdx.x * 64 + w * 16;
    if (row0 >= N) return;
    int nr = N - row0; if (nr > 16) nr = 16;

    const uint_t* h1 = (const uint_t*)h;

    uint_t v[16];
    int    bb[16];
    #pragma unroll
    for (int i = 0; i < 16; i++) {
        int r = (i < nr) ? row0 + i : row0;
        v[i]  = h1[(size_t)r * 64 + lane];
        bb[i] = batch[r];
    }

    float ax = 0.f, ay = 0.f;
    int cnt = 0;
    int cur = bb[0];
    #pragma unroll
    for (int i = 0; i < 16; i++) {
        if (i < nr) {
            if (bb[i] != cur) {
                atomicAdd(&pooled[(size_t)cur * 128 + lane * 2],     ax);
                atomicAdd(&pooled[(size_t)cur * 128 + lane * 2 + 1], ay);
                if (lane == 0) atomicAdd(&counts[cur], cnt);
                ax = 0.f; ay = 0.f; cnt = 0; cur = bb[i];
            }
            ax += bfl(v[i]);
            ay += bfh(v[i]);
            cnt++;
        }
    }
    atomicAdd(&pooled[(size_t)cur * 128 + lane * 2],     ax);
    atomicAdd(&pooled[(size_t)cur * 128 + lane * 2 + 1], ay);
    if (lane == 0) atomicAdd(&counts[cur], cnt);
}

// ---------------- MLP head ----------------

__global__ void k_mlp(const float* __restrict__ pooled, const int* __restrict__ counts,
                      const float* __restrict__ Wc1, const float* __restrict__ bc1,
                      const float* __restrict__ Wc2, const float* __restrict__ bc2,
                      float* __restrict__ out, int G) {
    int g = blockIdx.x;
    int j = threadIdx.x;    // 0..63
    __shared__ float pm[128];
    __shared__ float z[64];

    float invc = 1.0f / fmaxf((float)counts[g], 1.0f);
    pm[j]      = pooled[(size_t)g * 128 + j] * invc;
    pm[j + 64] = pooled[(size_t)g * 128 + 64 + j] * invc;
    __syncthreads();

    float a = bc1[j];
    #pragma unroll 8
    for (int k = 0; k < 128; k++) a += pm[k] * Wc1[k * 64 + j];
    z[j] = fmaxf(a, 0.f);
    __syncthreads();

    if (j < 8) {
        float o = bc2[j];
        #pragma unroll 8
        for (int k = 0; k < 64; k++) o += z[k] * Wc2[k * 8 + j];
        out[(size_t)g * 8 + j] = o;
    }
}

// ---------------- launch ----------------

extern "C" void kernel_launch(void* const* d_in, const int* in_sizes, int n_in,
                              void* d_out, int out_size, void* d_ws, size_t ws_size,
                              hipStream_t stream) {
    const float* x    = (const float*)d_in[0];
    const int*   ei   = (const int*)d_in[1];
    const int*   batch= (const int*)d_in[2];
    const float* W1   = (const float*)d_in[4];
    const float* b1   = (const float*)d_in[5];
    const float* W2   = (const float*)d_in[6];
    const float* b2   = (const float*)d_in[7];
    const float* Wc1  = (const float*)d_in[8];
    const float* bc1  = (const float*)d_in[9];
    const float* Wc2  = (const float*)d_in[10];
    const float* bc2  = (const float*)d_in[11];
    float* out = (float*)d_out;

    const int N = in_sizes[0] / 128;
    const int E = in_sizes[1] / 2;
    const int G = out_size / 8;

    const int* src = ei;
    const int* dst = ei + E;

    const int NBK = DIV_UP(N, 256);     // buckets of 256 nodes
    const int NB1 = DIV_UP(E, CH);      // partition blocks

    char* p = (char*)d_ws;
    auto alloc = [&](size_t bytes) {
        char* q = p;
        p += (bytes + 255) & ~(size_t)255;
        return q;
    };
    ushort_t* bufG1    = (ushort_t*)alloc((size_t)(N + 1) * 128 * 2);  // g1 / h2 (bf16) + zero row
    ushort_t* bufG2    = (ushort_t*)alloc((size_t)(N + 1) * 128 * 2);  // g2 (bf16) + zero row
    ushort_t* bufH     = (ushort_t*)alloc((size_t)N * 128 * 2);        // h1 (bf16)
    int*      rowptr   = (int*)     alloc(((size_t)N + 1) * 4);
    int*      colA     = (int*)     alloc((size_t)E * 4 + 256);
    float*    inv_sqrt = (float*)   alloc((size_t)N * 4);
    int*      blk_hist = (int*)     alloc((size_t)NBK * NB1 * 4);
    int*      blk_off  = (int*)     alloc((size_t)NBK * NB1 * 4);
    int*      bkt_base = (int*)     alloc(((size_t)NBK + 1) * 4);
    int*      bktT     = (int*)     alloc((size_t)NBK * 4);
    int*      doneF    = (int*)     alloc(256);
    ushort_t* wT1      = (ushort_t*)alloc(128 * 128 * 2);
    ushort_t* wT2      = (ushort_t*)alloc(128 * 128 * 2);
    float*    pooled   = (float*)   alloc((size_t)G * 128 * 4);
    int*      counts   = (int*)     alloc((size_t)G * 4);

    unsigned int* part_arr = (unsigned int*)bufG1;   // consumed before GEMM1 writes bufG1
    ushort_t* zrow1 = bufG1 + (size_t)N * 128;
    ushort_t* zrow2 = bufG2 + (size_t)N * 128;

    // setup + histogram (fused) ; CSR build
    k_setup_hist<<<NB1 + 161, 256, 0, stream>>>(dst, E, NBK, NB1, blk_hist,
                                                W1, W2, wT1, wT2, pooled, counts, G,
                                                zrow1, zrow2, doneF);
    k_rowscan<<<NBK, 256, 0, stream>>>(blk_hist, blk_off, bktT, bkt_base, doneF, NBK, NB1, E);
    k_scatter1<<<NB1, 256, 0, stream>>>(src, dst, E, NBK, NB1, blk_off, bkt_base, part_arr);
    k_sortfill<<<NBK, 512, 0, stream>>>(part_arr, bkt_base, N, E, colA, rowptr, inv_sqrt);

    // layer 1: MFMA GEMM (f32 in) -> g1 bf16 ; aggregate -> h1 bf16
    k_gemm_mfma<false><<<DIV_UP(N, 128), 256, 0, stream>>>(x, wT1, inv_sqrt, bufG1, N);
    k_agg<<<DIV_UP(N, 4), 256, 0, stream>>>(bufG1, rowptr, colA, inv_sqrt, b1, bufH, N);

    // layer 2: MFMA GEMM (bf16 in) -> g2 bf16 ; aggregate -> h2 bf16 (reuse bufG1)
    k_gemm_mfma<true><<<DIV_UP(N, 128), 256, 0, stream>>>(bufH, wT2, inv_sqrt, bufG2, N);
    k_agg<<<DIV_UP(N, 4), 256, 0, stream>>>(bufG2, rowptr, colA, inv_sqrt, b2, bufG1, N);

    // pool + head
    k_pool<<<DIV_UP(N, 64), 256, 0, stream>>>(bufG1, batch, pooled, counts, N);
    k_mlp<<<G, 64, 0, stream>>>(pooled, counts, Wc1, bc1, Wc2, bc2, out, G);
}